// Round 1
// baseline (6314.096 us; speedup 1.0000x reference)
//
#include <hip/hip_runtime.h>
#include <math.h>

#define BATCH 128
#define NEMB 512
#define LAT 32

// ---------------- workspace layout (floats) ----------------
// buf1 : 16777216 @ 0          (h1 [128,32,64,64], later g2 [128,32,64,64])
// buf2 :  8388608 @ 16777216   (h2 [128,64,32,32], later g1 [128,64,32,32])
// z    :  1048576 @ 25165824   ([128,32,16,16])
// zq   :  1048576 @ 26214400   ([128,32,16,16])
// accum:      320 @ 27262976   [0..255] recon buckets, [256] vq sum
// e2   :      512 @ 27263296   per-code ||e||^2
static const size_t OFF_BUF1 = 0;
static const size_t OFF_BUF2 = 16777216;
static const size_t OFF_Z    = 25165824;
static const size_t OFF_ZQ   = 26214400;
static const size_t OFF_ACC  = 27262976;
static const size_t OFF_E2   = 27263296;

__global__ void init_kernel(const float* __restrict__ emb,
                            float* __restrict__ accum,
                            float* __restrict__ e2) {
    int t = blockIdx.x * blockDim.x + threadIdx.x;   // 2 blocks x 256
    if (t < 320) accum[t] = 0.f;
    if (t < NEMB) {
        float s = 0.f;
        #pragma unroll
        for (int c = 0; c < LAT; ++c) { float e = emb[t * LAT + c]; s = fmaf(e, e, s); }
        e2[t] = s;
    }
}

// ---------------- direct conv k=4 s=2 p=1, one thread per output ----------------
template <int CIN, bool RELU>
__global__ void conv_k4s2(const float* __restrict__ x, const float* __restrict__ w,
                          const float* __restrict__ bias, float* __restrict__ out,
                          int CO, int HI, int WI) {
    const int HO = HI >> 1, WO = WI >> 1;
    int idx = blockIdx.x * 256 + threadIdx.x;
    int ox = idx % WO; int t = idx / WO;
    int oy = t % HO;  t /= HO;
    int co = t % CO;  int n = t / CO;

    float acc = bias[co];
    const int iy0 = 2 * oy - 1, ix0 = 2 * ox - 1;
    const float* wp = w + (size_t)co * CIN * 16;
    const float* xp = x + (size_t)n * CIN * HI * WI;
    #pragma unroll 4
    for (int ci = 0; ci < CIN; ++ci) {
        const float* xc = xp + (size_t)ci * HI * WI;
        const float* wc = wp + ci * 16;
        #pragma unroll
        for (int ky = 0; ky < 4; ++ky) {
            int iy = iy0 + ky;
            if (iy < 0 || iy >= HI) continue;
            #pragma unroll
            for (int kx = 0; kx < 4; ++kx) {
                int ix = ix0 + kx;
                if (ix < 0 || ix >= WI) continue;
                acc = fmaf(xc[iy * WI + ix], wc[ky * 4 + kx], acc);
            }
        }
    }
    out[idx] = RELU ? fmaxf(acc, 0.f) : acc;
}

// ---------------- direct transpose-conv k=4 s=2 p=1 ----------------
// y[n,co,oy,ox] = b[co] + sum_ci sum_{ky,kx valid} x[n,ci,iy,ix] * w[ci,co,ky,kx]
//   iy = (oy+1-ky)/2 for ky in {ky0, ky0+2}, ky0=(oy+1)&1 ; same for x.
// MODE 0: relu      MODE 1: sigmoid + accumulate (y - ref)^2 into buckets
template <int CIN, int CO_, int MODE>
__global__ void deconv_k4s2(const float* __restrict__ x, const float* __restrict__ w,
                            const float* __restrict__ bias, float* __restrict__ out,
                            const float* __restrict__ ref, float* __restrict__ buckets,
                            int HI, int WI) {
    const int HO = HI * 2, WO = WI * 2;
    int idx = blockIdx.x * 256 + threadIdx.x;
    int ox = idx % WO; int t = idx / WO;
    int oy = t % HO;  t /= HO;
    int co = t % CO_; int n = t / CO_;

    const int ky0 = (oy + 1) & 1;
    const int iyA = (oy + 1 - ky0) >> 1;   // tap ky0
    const int iyB = iyA - 1;               // tap ky0+2
    const bool vA = (iyA < HI);
    const bool vB = (iyB >= 0);
    const int kx0 = (ox + 1) & 1;
    const int ixA = (ox + 1 - kx0) >> 1;
    const int ixB = ixA - 1;
    const bool uA = (ixA < WI);
    const bool uB = (ixB >= 0);

    float acc = bias[co];
    const float* wb = w + co * 16;
    const float* xb = x + (size_t)n * CIN * HI * WI;
    #pragma unroll 4
    for (int ci = 0; ci < CIN; ++ci) {
        const float* xc = xb + (size_t)ci * HI * WI;
        const float* wc = wb + (size_t)ci * CO_ * 16;
        if (vA && uA) acc = fmaf(xc[iyA * WI + ixA], wc[ky0 * 4 + kx0],           acc);
        if (vA && uB) acc = fmaf(xc[iyA * WI + ixB], wc[ky0 * 4 + kx0 + 2],       acc);
        if (vB && uA) acc = fmaf(xc[iyB * WI + ixA], wc[(ky0 + 2) * 4 + kx0],     acc);
        if (vB && uB) acc = fmaf(xc[iyB * WI + ixB], wc[(ky0 + 2) * 4 + kx0 + 2], acc);
    }
    if (MODE == 0) {
        out[idx] = fmaxf(acc, 0.f);
    } else {
        float s = 1.f / (1.f + __expf(-acc));
        out[idx] = s;
        float d = s - ref[idx];
        float local = d * d;
        #pragma unroll
        for (int off = 32; off; off >>= 1) local += __shfl_down(local, off, 64);
        if ((threadIdx.x & 63) == 0) atomicAdd(&buckets[blockIdx.x & 255], local);
    }
}

// ---------------- fused VQ: argmin + gather + e-loss partial ----------------
// z layout [128, 32, 16, 16]; each thread owns one spatial vector (32 floats, stride 256).
__global__ void vq_kernel(const float* __restrict__ z, const float* __restrict__ emb,
                          const float* __restrict__ e2, float* __restrict__ zq,
                          float* __restrict__ vq_accum) {
    __shared__ float se[NEMB * LAT];   // 64 KB
    int tid = threadIdx.x;
    for (int i = tid; i < NEMB * LAT; i += 256) se[i] = emb[i];
    __syncthreads();

    int g = blockIdx.x * 256 + tid;    // 0..32767
    int n = g >> 8;
    int pos = g & 255;
    const float* zp = z + (size_t)n * LAT * 256 + pos;

    float zv[LAT], m2z[LAT];
    #pragma unroll
    for (int c = 0; c < LAT; ++c) { zv[c] = zp[(size_t)c * 256]; m2z[c] = -2.f * zv[c]; }

    const float4* se4 = (const float4*)se;
    float best = 1e30f; int bk = 0;
    for (int k = 0; k < NEMB; ++k) {
        float d = e2[k];
        #pragma unroll
        for (int j = 0; j < 8; ++j) {
            float4 e4 = se4[k * 8 + j];
            d = fmaf(m2z[4 * j + 0], e4.x, d);
            d = fmaf(m2z[4 * j + 1], e4.y, d);
            d = fmaf(m2z[4 * j + 2], e4.z, d);
            d = fmaf(m2z[4 * j + 3], e4.w, d);
        }
        if (d < best) { best = d; bk = k; }   // strict <  == argmin first-index tie rule
    }

    float local = 0.f;
    float* zqp = zq + (size_t)n * LAT * 256 + pos;
    #pragma unroll
    for (int c = 0; c < LAT; ++c) {
        float e = se[bk * LAT + c];
        float dd = e - zv[c];
        local = fmaf(dd, dd, local);
        zqp[(size_t)c * 256] = e;
    }
    #pragma unroll
    for (int off = 32; off; off >>= 1) local += __shfl_down(local, off, 64);
    if ((tid & 63) == 0) atomicAdd(vq_accum, local);
}

__global__ void finalize_kernel(const float* __restrict__ accum, float* __restrict__ out,
                                int out_size) {
    int tid = threadIdx.x;  // 256
    float v = accum[tid];
    #pragma unroll
    for (int off = 32; off; off >>= 1) v += __shfl_down(v, off, 64);
    __shared__ float s[4];
    if ((tid & 63) == 0) s[tid >> 6] = v;
    __syncthreads();
    if (tid == 0) {
        float tot = s[0] + s[1] + s[2] + s[3];
        out[out_size - 2] = tot / 6291456.f;                       // recon_loss
        out[out_size - 1] = 1.25f * accum[256] / 1048576.f;        // vq_loss
    }
}

extern "C" void kernel_launch(void* const* d_in, const int* in_sizes, int n_in,
                              void* d_out, int out_size, void* d_ws, size_t ws_size,
                              hipStream_t stream) {
    const float* x   = (const float*)d_in[0];
    const float* w1  = (const float*)d_in[1];
    const float* b1  = (const float*)d_in[2];
    const float* w2  = (const float*)d_in[3];
    const float* b2  = (const float*)d_in[4];
    const float* w3  = (const float*)d_in[5];
    const float* b3  = (const float*)d_in[6];
    const float* emb = (const float*)d_in[7];
    const float* d1  = (const float*)d_in[8];
    const float* db1 = (const float*)d_in[9];
    const float* d2  = (const float*)d_in[10];
    const float* db2 = (const float*)d_in[11];
    const float* d3  = (const float*)d_in[12];
    const float* db3 = (const float*)d_in[13];

    float* ws   = (float*)d_ws;
    float* buf1 = ws + OFF_BUF1;
    float* buf2 = ws + OFF_BUF2;
    float* z    = ws + OFF_Z;
    float* zq   = ws + OFF_ZQ;
    float* acc  = ws + OFF_ACC;
    float* e2   = ws + OFF_E2;
    float* out  = (float*)d_out;

    // init accumulators + per-code ||e||^2
    init_kernel<<<2, 256, 0, stream>>>(emb, acc, e2);

    // encoder
    conv_k4s2<3, true ><<<65536, 256, 0, stream>>>(x,    w1, b1, buf1, 32, 128, 128);
    conv_k4s2<32, true><<<32768, 256, 0, stream>>>(buf1, w2, b2, buf2, 64, 64, 64);
    conv_k4s2<64, false><<<4096, 256, 0, stream>>>(buf2, w3, b3, z,    32, 32, 32);

    // vector quantization (fused argmin/gather/e-loss)
    vq_kernel<<<128, 256, 0, stream>>>(z, emb, e2, zq, acc + 256);

    // decoder (g1 reuses buf2, g2 reuses buf1)
    deconv_k4s2<32, 64, 0><<<32768, 256, 0, stream>>>(zq,   d1, db1, buf2, nullptr, nullptr, 16, 16);
    deconv_k4s2<64, 32, 0><<<65536, 256, 0, stream>>>(buf2, d2, db2, buf1, nullptr, nullptr, 32, 32);
    deconv_k4s2<32, 3, 1><<<24576, 256, 0, stream>>>(buf1, d3, db3, out,  x,       acc,      64, 64);

    finalize_kernel<<<1, 256, 0, stream>>>(acc, out, out_size);
}

// Round 2
// 787.769 us; speedup vs baseline: 8.0152x; 8.0152x over previous
//
#include <hip/hip_runtime.h>
#include <math.h>

#define NEMB 512
#define LAT 32

// ---------------- workspace layout (floats) ----------------
static const size_t OFF_BUF1 = 0;          // h1 [128,32,64,64] / g2 [128,32,64,64]
static const size_t OFF_BUF2 = 16777216;   // h2 [128,64,32,32] / g1 [128,64,32,32]
static const size_t OFF_Z    = 25165824;   // z  [128,32,16,16]
static const size_t OFF_ZQ   = 26214400;   // zq [128,32,16,16]
static const size_t OFF_ACC  = 27262976;   // [0..255] recon buckets, [256] vq sum
static const size_t OFF_E2   = 27263296;   // per-code ||e||^2

__global__ void init_kernel(const float* __restrict__ emb,
                            float* __restrict__ accum,
                            float* __restrict__ e2) {
    int t = blockIdx.x * blockDim.x + threadIdx.x;
    if (t < 320) accum[t] = 0.f;
    if (t < NEMB) {
        float s = 0.f;
        #pragma unroll
        for (int c = 0; c < LAT; ++c) { float e = emb[t * LAT + c]; s = fmaf(e, e, s); }
        e2[t] = s;
    }
}

// =================================================================
// Tiled forward conv k=4 s=2 p=1.
// Block: one n, COT output channels, TH x TW output tile. 256 threads,
// each owns PPT adjacent-ox pixels for all COT channels.
// =================================================================
template <int CIN, int CICH, int CO, int COT, int HI, int WI,
          int TH, int TW, int PPT, bool RELU>
__global__ __launch_bounds__(256, 2)
void conv_tiled(const float* __restrict__ x, const float* __restrict__ w,
                const float* __restrict__ bias, float* __restrict__ out) {
    const int HO = HI / 2, WO = WI / 2;
    const int TR = 2 * TH + 2, TC = 2 * TW + 2, TCP = TC + 1;
    const int NTX = WO / TW, NTY = HO / TH, NCOB = CO / COT;
    const int NCG = TW / PPT;                 // col groups (TH*NCG == 256)

    __shared__ float sx[CICH * TR * TCP];
    __shared__ float sw[CICH * COT * 16];

    int bid = blockIdx.x;
    const int tx  = bid % NTX;  bid /= NTX;
    const int ty  = bid % NTY;  bid /= NTY;
    const int cob = bid % NCOB; const int n = bid / NCOB;

    const int tid = threadIdx.x;
    const int cg  = tid % NCG;
    const int tr  = tid / NCG;
    const int tc0 = cg * PPT;

    float acc[COT * PPT];
    #pragma unroll
    for (int co = 0; co < COT; ++co) {
        float b = bias[cob * COT + co];
        #pragma unroll
        for (int p = 0; p < PPT; ++p) acc[co * PPT + p] = b;
    }

    const int iy0 = 2 * (ty * TH) - 1;
    const int ix0 = 2 * (tx * TW) - 1;

    for (int ck = 0; ck < CIN / CICH; ++ck) {
        __syncthreads();
        // ---- stage x tile (zero padded) ----
        for (int l = tid; l < CICH * TR * TC; l += 256) {
            int c   = l / (TR * TC);
            int rem = l % (TR * TC);
            int r   = rem / TC;
            int col = rem % TC;
            int gy = iy0 + r, gx = ix0 + col;
            float v = 0.f;
            if (gy >= 0 && gy < HI && gx >= 0 && gx < WI)
                v = x[(((size_t)n * CIN + ck * CICH + c) * HI + gy) * WI + gx];
            sx[(c * TR + r) * TCP + col] = v;
        }
        // ---- stage weights chunk: sw[ci][co][16] ----
        for (int l = tid; l < CICH * COT * 16; l += 256) {
            int ci = l / (COT * 16);
            int co = (l / 16) % COT;
            int k  = l % 16;
            sw[l] = w[((size_t)(cob * COT + co) * CIN + ck * CICH + ci) * 16 + k];
        }
        __syncthreads();

        for (int ci = 0; ci < CICH; ++ci) {
            float tap[4][2 * PPT + 2];
            #pragma unroll
            for (int ky = 0; ky < 4; ++ky)
                #pragma unroll
                for (int j = 0; j < 2 * PPT + 2; ++j)
                    tap[ky][j] = sx[(ci * TR + 2 * tr + ky) * TCP + 2 * tc0 + j];

            #pragma unroll
            for (int co = 0; co < COT; ++co) {
                const float4* wv = (const float4*)&sw[(ci * COT + co) * 16];
                float4 w0 = wv[0], w1 = wv[1], w2 = wv[2], w3 = wv[3];
                float wk[16] = {w0.x, w0.y, w0.z, w0.w, w1.x, w1.y, w1.z, w1.w,
                                w2.x, w2.y, w2.z, w2.w, w3.x, w3.y, w3.z, w3.w};
                #pragma unroll
                for (int p = 0; p < PPT; ++p) {
                    float a = acc[co * PPT + p];
                    #pragma unroll
                    for (int ky = 0; ky < 4; ++ky) {
                        a = fmaf(tap[ky][2 * p + 0], wk[ky * 4 + 0], a);
                        a = fmaf(tap[ky][2 * p + 1], wk[ky * 4 + 1], a);
                        a = fmaf(tap[ky][2 * p + 2], wk[ky * 4 + 2], a);
                        a = fmaf(tap[ky][2 * p + 3], wk[ky * 4 + 3], a);
                    }
                    acc[co * PPT + p] = a;
                }
            }
        }
    }

    // ---- write out ----
    const int oy = ty * TH + tr;
    const int oxb = tx * TW + tc0;
    #pragma unroll
    for (int co = 0; co < COT; ++co) {
        size_t oi = (((size_t)n * CO + cob * COT + co) * HO + oy) * WO + oxb;
        if (PPT == 2) {
            float2 st;
            st.x = RELU ? fmaxf(acc[co * PPT + 0], 0.f) : acc[co * PPT + 0];
            st.y = RELU ? fmaxf(acc[co * PPT + 1], 0.f) : acc[co * PPT + 1];
            *(float2*)&out[oi] = st;
        } else {
            #pragma unroll
            for (int p = 0; p < PPT; ++p) {
                float v = acc[co * PPT + p];
                out[oi + p] = RELU ? fmaxf(v, 0.f) : v;
            }
        }
    }
}

// =================================================================
// Tiled transpose-conv k=4 s=2 p=1. Each output pixel has exactly
// 2x2 taps, kernel-row parity fixed per output row.
// MODE 0: relu    MODE 1: sigmoid + (y-ref)^2 bucket accumulate
// =================================================================
template <int CIN, int CICH, int CO, int COT, int HI, int WI,
          int TH, int TW, int PPT, int MODE>
__global__ __launch_bounds__(256, 2)
void deconv_tiled(const float* __restrict__ x, const float* __restrict__ w,
                  const float* __restrict__ bias, float* __restrict__ out,
                  const float* __restrict__ ref, float* __restrict__ buckets) {
    const int HO = 2 * HI, WO = 2 * WI;
    const int TR = TH / 2 + 2, TC = TW / 2 + 2, TCP = TC + 1;
    const int NTX = WO / TW, NTY = HO / TH, NCOB = CO / COT;
    const int NCG = TW / PPT;
    const int NTAPC = PPT / 2 + 2;            // tap cols per row

    __shared__ float sx[CICH * TR * TCP];
    __shared__ float sw[CICH * COT * 16];

    int bid = blockIdx.x;
    const int tx  = bid % NTX;  bid /= NTX;
    const int ty  = bid % NTY;  bid /= NTY;
    const int cob = bid % NCOB; const int n = bid / NCOB;

    const int tid = threadIdx.x;
    const int cg  = tid % NCG;
    const int tr  = tid / NCG;
    const int tc0 = cg * PPT;
    const int q   = tc0 / 2;                  // tap col base (local)

    const int ky0   = (tr + 1) & 1;           // oy_base even
    const int iyA_l = ((tr + 1 - ky0) >> 1) + 1;
    const int iyB_l = iyA_l - 1;

    float acc[COT * PPT];
    #pragma unroll
    for (int co = 0; co < COT; ++co) {
        float b = bias[cob * COT + co];
        #pragma unroll
        for (int p = 0; p < PPT; ++p) acc[co * PPT + p] = b;
    }

    const int iy_org = (ty * TH) / 2 - 1;
    const int ix_org = (tx * TW) / 2 - 1;

    for (int ck = 0; ck < CIN / CICH; ++ck) {
        __syncthreads();
        for (int l = tid; l < CICH * TR * TC; l += 256) {
            int c   = l / (TR * TC);
            int rem = l % (TR * TC);
            int r   = rem / TC;
            int col = rem % TC;
            int gy = iy_org + r, gx = ix_org + col;
            float v = 0.f;
            if (gy >= 0 && gy < HI && gx >= 0 && gx < WI)
                v = x[(((size_t)n * CIN + ck * CICH + c) * HI + gy) * WI + gx];
            sx[(c * TR + r) * TCP + col] = v;
        }
        // w layout [CIN][CO][4][4] -> sw[ci][co][16]
        for (int l = tid; l < CICH * COT * 16; l += 256) {
            int ci = l / (COT * 16);
            int co = (l / 16) % COT;
            int k  = l % 16;
            sw[l] = w[((size_t)(ck * CICH + ci) * CO + cob * COT + co) * 16 + k];
        }
        __syncthreads();

        for (int ci = 0; ci < CICH; ++ci) {
            float tA[NTAPC], tB[NTAPC];
            #pragma unroll
            for (int j = 0; j < NTAPC; ++j) {
                tA[j] = sx[(ci * TR + iyA_l) * TCP + q + j];
                tB[j] = sx[(ci * TR + iyB_l) * TCP + q + j];
            }
            #pragma unroll
            for (int co = 0; co < COT; ++co) {
                const float4* wv = (const float4*)&sw[(ci * COT + co) * 16];
                float4 wA = wv[ky0];          // kernel row ky0   (pairs row iyA)
                float4 wB = wv[ky0 + 2];      // kernel row ky0+2 (pairs row iyB)
                #pragma unroll
                for (int p = 0; p < PPT; ++p) {
                    const int A = (p + 3) >> 1;
                    const int B = (p + 1) >> 1;
                    float a = acc[co * PPT + p];
                    if (((p + 1) & 1) == 1) { // kx0 = 1
                        a = fmaf(tA[A], wA.y, a);
                        a = fmaf(tA[B], wA.w, a);
                        a = fmaf(tB[A], wB.y, a);
                        a = fmaf(tB[B], wB.w, a);
                    } else {                  // kx0 = 0
                        a = fmaf(tA[A], wA.x, a);
                        a = fmaf(tA[B], wA.z, a);
                        a = fmaf(tB[A], wB.x, a);
                        a = fmaf(tB[B], wB.z, a);
                    }
                    acc[co * PPT + p] = a;
                }
            }
        }
    }

    const int oy  = ty * TH + tr;
    const int oxb = tx * TW + tc0;
    float local = 0.f;
    #pragma unroll
    for (int co = 0; co < COT; ++co) {
        size_t oi = (((size_t)n * CO + cob * COT + co) * HO + oy) * WO + oxb;
        if (MODE == 0) {
            if (PPT == 4) {
                float4 st;
                st.x = fmaxf(acc[co * PPT + 0], 0.f);
                st.y = fmaxf(acc[co * PPT + 1], 0.f);
                st.z = fmaxf(acc[co * PPT + 2], 0.f);
                st.w = fmaxf(acc[co * PPT + 3], 0.f);
                *(float4*)&out[oi] = st;
            } else {
                #pragma unroll
                for (int p = 0; p < PPT; ++p) out[oi + p] = fmaxf(acc[co * PPT + p], 0.f);
            }
        } else {
            float4 rf = *(const float4*)&ref[oi];
            float4 st;
            st.x = 1.f / (1.f + __expf(-acc[co * PPT + 0]));
            st.y = 1.f / (1.f + __expf(-acc[co * PPT + 1]));
            st.z = 1.f / (1.f + __expf(-acc[co * PPT + 2]));
            st.w = 1.f / (1.f + __expf(-acc[co * PPT + 3]));
            *(float4*)&out[oi] = st;
            float d0 = st.x - rf.x, d1 = st.y - rf.y, d2 = st.z - rf.z, d3 = st.w - rf.w;
            local += d0 * d0 + d1 * d1 + d2 * d2 + d3 * d3;
        }
    }
    if (MODE == 1) {
        #pragma unroll
        for (int off = 32; off; off >>= 1) local += __shfl_down(local, off, 64);
        if ((tid & 63) == 0) atomicAdd(&buckets[blockIdx.x & 255], local);
    }
}

// ---------------- fused VQ: argmin + gather + e-loss partial ----------------
__global__ void vq_kernel(const float* __restrict__ z, const float* __restrict__ emb,
                          const float* __restrict__ e2, float* __restrict__ zq,
                          float* __restrict__ vq_accum) {
    __shared__ float se[NEMB * LAT];   // 64 KB
    int tid = threadIdx.x;             // 128 threads
    for (int i = tid; i < NEMB * LAT / 4; i += 128)
        ((float4*)se)[i] = ((const float4*)emb)[i];
    __syncthreads();

    int g = blockIdx.x * 128 + tid;    // 0..32767
    int n = g >> 8;
    int pos = g & 255;
    const float* zp = z + (size_t)n * LAT * 256 + pos;

    float zv[LAT], m2z[LAT];
    #pragma unroll
    for (int c = 0; c < LAT; ++c) { zv[c] = zp[(size_t)c * 256]; m2z[c] = -2.f * zv[c]; }

    const float4* se4 = (const float4*)se;
    float best = 1e30f; int bk = 0;
    for (int k = 0; k < NEMB; ++k) {
        float d = e2[k];
        #pragma unroll
        for (int j = 0; j < 8; ++j) {
            float4 e4 = se4[k * 8 + j];
            d = fmaf(m2z[4 * j + 0], e4.x, d);
            d = fmaf(m2z[4 * j + 1], e4.y, d);
            d = fmaf(m2z[4 * j + 2], e4.z, d);
            d = fmaf(m2z[4 * j + 3], e4.w, d);
        }
        if (d < best) { best = d; bk = k; }   // strict < == first-index tie rule
    }

    float local = 0.f;
    float* zqp = zq + (size_t)n * LAT * 256 + pos;
    #pragma unroll
    for (int c = 0; c < LAT; ++c) {
        float e = se[bk * LAT + c];
        float dd = e - zv[c];
        local = fmaf(dd, dd, local);
        zqp[(size_t)c * 256] = e;
    }
    #pragma unroll
    for (int off = 32; off; off >>= 1) local += __shfl_down(local, off, 64);
    if ((tid & 63) == 0) atomicAdd(vq_accum, local);
}

__global__ void finalize_kernel(const float* __restrict__ accum, float* __restrict__ out,
                                int out_size) {
    int tid = threadIdx.x;  // 256
    float v = accum[tid];
    #pragma unroll
    for (int off = 32; off; off >>= 1) v += __shfl_down(v, off, 64);
    __shared__ float s[4];
    if ((tid & 63) == 0) s[tid >> 6] = v;
    __syncthreads();
    if (tid == 0) {
        float tot = s[0] + s[1] + s[2] + s[3];
        out[out_size - 2] = tot / 6291456.f;                 // recon_loss
        out[out_size - 1] = 1.25f * accum[256] / 1048576.f;  // vq_loss
    }
}

extern "C" void kernel_launch(void* const* d_in, const int* in_sizes, int n_in,
                              void* d_out, int out_size, void* d_ws, size_t ws_size,
                              hipStream_t stream) {
    const float* x   = (const float*)d_in[0];
    const float* w1  = (const float*)d_in[1];
    const float* b1  = (const float*)d_in[2];
    const float* w2  = (const float*)d_in[3];
    const float* b2  = (const float*)d_in[4];
    const float* w3  = (const float*)d_in[5];
    const float* b3  = (const float*)d_in[6];
    const float* emb = (const float*)d_in[7];
    const float* d1  = (const float*)d_in[8];
    const float* db1 = (const float*)d_in[9];
    const float* d2  = (const float*)d_in[10];
    const float* db2 = (const float*)d_in[11];
    const float* d3  = (const float*)d_in[12];
    const float* db3 = (const float*)d_in[13];

    float* ws   = (float*)d_ws;
    float* buf1 = ws + OFF_BUF1;
    float* buf2 = ws + OFF_BUF2;
    float* z    = ws + OFF_Z;
    float* zq   = ws + OFF_ZQ;
    float* acc  = ws + OFF_ACC;
    float* e2   = ws + OFF_E2;
    float* out  = (float*)d_out;

    init_kernel<<<2, 256, 0, stream>>>(emb, acc, e2);

    // encoder
    // conv1: 3->32, 128x128 -> 64x64
    conv_tiled<3, 3, 32, 32, 128, 128, 16, 32, 2, true>
        <<<128 * 1 * 4 * 2, 256, 0, stream>>>(x, w1, b1, buf1);
    // conv2: 32->64, 64x64 -> 32x32
    conv_tiled<32, 4, 64, 32, 64, 64, 16, 32, 2, true>
        <<<128 * 2 * 2 * 1, 256, 0, stream>>>(buf1, w2, b2, buf2);
    // conv3: 64->32, 32x32 -> 16x16
    conv_tiled<64, 8, 32, 8, 32, 32, 16, 16, 1, false>
        <<<128 * 4 * 1 * 1, 256, 0, stream>>>(buf2, w3, b3, z);

    // vector quantization
    vq_kernel<<<256, 128, 0, stream>>>(z, emb, e2, zq, acc + 256);

    // decoder
    // deconv1: 32->64, 16x16 -> 32x32
    deconv_tiled<32, 8, 64, 16, 16, 16, 32, 32, 4, 0>
        <<<128 * 4 * 1 * 1, 256, 0, stream>>>(zq, d1, db1, buf2, nullptr, nullptr);
    // deconv2: 64->32, 32x32 -> 64x64
    deconv_tiled<64, 8, 32, 32, 32, 32, 16, 64, 4, 0>
        <<<128 * 1 * 4 * 1, 256, 0, stream>>>(buf2, d2, db2, buf1, nullptr, nullptr);
    // deconv3: 32->3, 64x64 -> 128x128, fused sigmoid + recon loss
    deconv_tiled<32, 8, 3, 3, 64, 64, 16, 64, 4, 1>
        <<<128 * 1 * 8 * 2, 256, 0, stream>>>(buf1, d3, db3, out, x, acc);

    finalize_kernel<<<1, 256, 0, stream>>>(acc, out, out_size);
}

// Round 3
// 395.641 us; speedup vs baseline: 15.9591x; 1.9911x over previous
//
#include <hip/hip_runtime.h>
#include <math.h>

#define NEMB 512
#define LAT 32

typedef unsigned short u16;
typedef __attribute__((ext_vector_type(8))) short bf16x8;   // 8 bf16 in 4 VGPRs
typedef __attribute__((ext_vector_type(4))) float f32x4;

__device__ __forceinline__ u16 f2b(float f) {               // fp32 -> bf16 RTNE
    unsigned u = __builtin_bit_cast(unsigned, f);
    return (u16)((u + 0x7fffu + ((u >> 16) & 1u)) >> 16);
}
__device__ __forceinline__ float b2f(u16 h) {
    unsigned u = ((unsigned)h) << 16;
    return __builtin_bit_cast(float, u);
}

union V16 { uint4 u; u16 s[8]; };

// ---------------- workspace layout (BYTES) ----------------
static const size_t OFF_H1  = 0;          // h1 [128,64,64,32] bf16 (later g2 [128,64,64,32])
static const size_t OFF_H2  = 33554432;   // h2 [128,32,32,64] bf16 (later g1 [128,32,32,64])
static const size_t OFF_Z   = 50331648;   // z  [128,16,16,32] bf16
static const size_t OFF_ZQ  = 52428800;   // zq [128,16,16,32] bf16
static const size_t OFF_W2T = 54525952;   // [16][64][32] bf16
static const size_t OFF_W3T = 54591488;   // [16][32][64] bf16
static const size_t OFF_D1T = 54657024;   // [16][64][32] bf16
static const size_t OFF_D2T = 54722560;   // [16][32][64] bf16
static const size_t OFF_D3T = 54788096;   // [16][16][32] bf16 (co padded 3->16)
static const size_t OFF_ACC = 54804480;   // f32: [0..255] recon buckets, [256] vq sum
static const size_t OFF_E2  = 54806528;   // f32: per-code ||e||^2

__global__ void init_kernel(const float* __restrict__ emb,
                            float* __restrict__ accum,
                            float* __restrict__ e2) {
    int t = blockIdx.x * blockDim.x + threadIdx.x;
    if (t < 320) accum[t] = 0.f;
    if (t < NEMB) {
        float s = 0.f;
        #pragma unroll
        for (int c = 0; c < LAT; ++c) { float e = emb[t * LAT + c]; s = fmaf(e, e, s); }
        e2[t] = s;
    }
}

// ---- weight transforms ----
// conv: w [CO][CI][4][4] f32 -> wt [tau][CO][CI] bf16
__global__ void wt_conv_k(const float* __restrict__ w, u16* __restrict__ wt, int CO, int CI) {
    int t = blockIdx.x * 256 + threadIdx.x;
    if (t >= 16 * CO * CI) return;
    int ci = t % CI; int t2 = t / CI; int co = t2 % CO; int tau = t2 / CO;
    wt[t] = f2b(w[((size_t)co * CI + ci) * 16 + tau]);
}
// deconv: w [CI][CO][4][4] f32 -> wt [s][CO][CI] bf16, s = ry*8+rx*4+a*2+b
__global__ void wt_deconv_k(const float* __restrict__ w, u16* __restrict__ wt, int CO, int CI) {
    int t = blockIdx.x * 256 + threadIdx.x;
    if (t >= 16 * CO * CI) return;
    int ci = t % CI; int t2 = t / CI; int co = t2 % CO; int s = t2 / CO;
    int ry = (s >> 3) & 1, rx = (s >> 2) & 1, a = (s >> 1) & 1, b = s & 1;
    int ky = ((ry + 1) & 1) + 2 * a, kx = ((rx + 1) & 1) + 2 * b;
    wt[t] = f2b(w[((size_t)ci * CO + co) * 16 + ky * 4 + kx]);
}
// d3: [32ci][3co][4][4] f32 -> wt [s][16co_pad][32ci] bf16
__global__ void wt_d3_k(const float* __restrict__ w, u16* __restrict__ wt) {
    int t = blockIdx.x * 256 + threadIdx.x;
    if (t >= 16 * 16 * 32) return;
    int ci = t % 32; int co = (t / 32) % 16; int s = t / 512;
    int ry = (s >> 3) & 1, rx = (s >> 2) & 1, a = (s >> 1) & 1, b = s & 1;
    int ky = ((ry + 1) & 1) + 2 * a, kx = ((rx + 1) & 1) + 2 * b;
    wt[t] = (co < 3) ? f2b(w[((size_t)ci * 3 + co) * 16 + ky * 4 + kx]) : (u16)0;
}

// =================================================================
// conv1 direct: x NCHW f32 [128,3,128,128] -> h1 NHWC bf16 [128,64,64,32]
// =================================================================
__global__ __launch_bounds__(256)
void conv1_direct(const float* __restrict__ x, const float* __restrict__ w1,
                  const float* __restrict__ b1, u16* __restrict__ h1) {
    __shared__ float sx[3 * 34 * 35];
    __shared__ float sw[3 * 16 * 32];   // [ci][kykx][co]
    int bid = blockIdx.x;
    const int tx = bid % 4; bid /= 4;
    const int ty = bid % 4; const int n = bid / 4;
    const int tid = threadIdx.x, tr = tid >> 4, tc = tid & 15;

    for (int u = tid; u < 3 * 34 * 34; u += 256) {
        int c = u / 1156; int rem = u % 1156; int r = rem / 34; int col = rem % 34;
        int iy = ty * 32 - 1 + r, ix = tx * 32 - 1 + col;
        float v = 0.f;
        if (iy >= 0 && iy < 128 && ix >= 0 && ix < 128)
            v = x[(((size_t)n * 3 + c) * 128 + iy) * 128 + ix];
        sx[(c * 34 + r) * 35 + col] = v;
    }
    for (int l = tid; l < 1536; l += 256) {
        int co = l & 31, kykx = (l >> 5) & 15, ci = l >> 9;
        sw[l] = w1[((size_t)co * 3 + ci) * 16 + kykx];
    }
    __syncthreads();

    float acc[32];
    #pragma unroll
    for (int c = 0; c < 32; ++c) acc[c] = b1[c];

    for (int ci = 0; ci < 3; ++ci) {
        float tv[16];
        #pragma unroll
        for (int ky = 0; ky < 4; ++ky)
            #pragma unroll
            for (int kx = 0; kx < 4; ++kx)
                tv[ky * 4 + kx] = sx[(ci * 34 + 2 * tr + ky) * 35 + 2 * tc + kx];
        #pragma unroll
        for (int kk = 0; kk < 16; ++kk) {
            float t = tv[kk];
            const float4* wp = (const float4*)&sw[(ci * 16 + kk) * 32];
            #pragma unroll
            for (int q = 0; q < 8; ++q) {
                float4 wv = wp[q];
                acc[q * 4 + 0] = fmaf(t, wv.x, acc[q * 4 + 0]);
                acc[q * 4 + 1] = fmaf(t, wv.y, acc[q * 4 + 1]);
                acc[q * 4 + 2] = fmaf(t, wv.z, acc[q * 4 + 2]);
                acc[q * 4 + 3] = fmaf(t, wv.w, acc[q * 4 + 3]);
            }
        }
    }
    const int oy = ty * 16 + tr, ox = tx * 16 + tc;
    size_t base = (((size_t)n * 64 + oy) * 64 + ox) * 32;
    #pragma unroll
    for (int q = 0; q < 4; ++q) {
        V16 o;
        #pragma unroll
        for (int j = 0; j < 8; ++j) o.s[j] = f2b(fmaxf(acc[q * 8 + j], 0.f));
        *(uint4*)&h1[base + q * 8] = o.u;
    }
}

// =================================================================
// MFMA conv k4s2: NHWC bf16 in/out. Block: 4 waves, tile 4oy x BCOLS x CO.
// =================================================================
template <int CI, int CO, int HI, int WI, bool RELU>
__global__ __launch_bounds__(256)
void mfma_conv(const u16* __restrict__ xin, const u16* __restrict__ wt,
               const float* __restrict__ bias, u16* __restrict__ out) {
    constexpr int HO = HI / 2, WO = WI / 2;
    constexpr int BCOLS = (WO < 32) ? WO : 32;
    constexpr int XC = 2 * BCOLS + 2;
    constexpr int NCOLF = BCOLS / 16, NCOF = CO / 16, NCC = CI / 32;
    constexpr int CPU8 = CI / 8;
    __shared__ u16 sx[10 * XC * CI];

    int bid = blockIdx.x;
    constexpr int NBY = HO / 4, NTX = WO / BCOLS;
    const int tx = bid % NTX; bid /= NTX;
    const int by = bid % NBY; const int n = bid / NBY;
    const int oy0 = by * 4, ox0 = tx * BCOLS;
    const int tid = threadIdx.x, w = tid >> 6, lane = tid & 63;
    const int l15 = lane & 15, l4 = lane >> 4;

    // ---- stage x tile, swizzled ----
    const int iyb = 2 * oy0 - 1, ixb = 2 * ox0 - 1;
    for (int u = tid; u < 10 * XC * CPU8; u += 256) {
        int c8 = u % CPU8; int t2 = u / CPU8;
        int xc = t2 % XC; int r = t2 / XC;
        int iy = iyb + r, ix = ixb + xc;
        uint4 v = {0, 0, 0, 0};
        if (iy >= 0 && iy < HI && ix >= 0 && ix < WI)
            v = *(const uint4*)&xin[(((size_t)n * HI + iy) * WI + ix) * CI + c8 * 8];
        int byte = ((r * XC + xc) * CI + c8 * 8) * 2;
        byte ^= ((xc >> 1) & 7) << 4;
        *(uint4*)&sx[byte >> 1] = v;
    }
    __syncthreads();

    f32x4 acc[NCOLF][NCOF];
    #pragma unroll
    for (int pf = 0; pf < NCOLF; ++pf)
        #pragma unroll
        for (int cf = 0; cf < NCOF; ++cf) {
            float bv = bias[cf * 16 + l15];
            acc[pf][cf] = (f32x4){bv, bv, bv, bv};
        }

    #pragma unroll 2
    for (int tau = 0; tau < 16; ++tau) {
        const int ky = tau >> 2, kx = tau & 3;
        const int r = 2 * w + ky;
        #pragma unroll
        for (int cc = 0; cc < NCC; ++cc) {
            bf16x8 b[NCOF];
            #pragma unroll
            for (int cf = 0; cf < NCOF; ++cf)
                b[cf] = *(const bf16x8*)&wt[((size_t)(tau * CO + cf * 16 + l15)) * CI + cc * 32 + l4 * 8];
            bf16x8 a[NCOLF];
            #pragma unroll
            for (int pf = 0; pf < NCOLF; ++pf) {
                int xc = 2 * (pf * 16 + l15) + kx;
                int byte = ((r * XC + xc) * CI + cc * 32 + l4 * 8) * 2;
                byte ^= ((xc >> 1) & 7) << 4;
                a[pf] = *(const bf16x8*)&sx[byte >> 1];
            }
            #pragma unroll
            for (int pf = 0; pf < NCOLF; ++pf)
                #pragma unroll
                for (int cf = 0; cf < NCOF; ++cf)
                    acc[pf][cf] = __builtin_amdgcn_mfma_f32_16x16x32_bf16(
                        a[pf], b[cf], acc[pf][cf], 0, 0, 0);
        }
    }

    const int oy = oy0 + w;
    #pragma unroll
    for (int pf = 0; pf < NCOLF; ++pf)
        #pragma unroll
        for (int cf = 0; cf < NCOF; ++cf)
            #pragma unroll
            for (int rg = 0; rg < 4; ++rg) {
                int ox = ox0 + pf * 16 + l4 * 4 + rg;
                float v = acc[pf][cf][rg];
                if (RELU) v = fmaxf(v, 0.f);
                out[(((size_t)n * HO + oy) * WO + ox) * CO + cf * 16 + l15] = f2b(v);
            }
}

// =================================================================
// MFMA deconv k4s2 (phase decomposition), output rows oy = 2q + RY.
// MODE 0: relu -> bf16 NHWC.  MODE 1: sigmoid -> f32 NCHW (co<3) + loss.
// =================================================================
template <int CI, int CO, int HI, int WI, int RY, int MODE>
__global__ __launch_bounds__(256)
void mfma_deconv(const u16* __restrict__ xin, const u16* __restrict__ wt,
                 const float* __restrict__ bias, void* __restrict__ outp,
                 const float* __restrict__ ref, float* __restrict__ buckets) {
    constexpr int HO = 2 * HI, WO = 2 * WI;
    constexpr int BCOLS = (WI < 32) ? WI : 32;
    constexpr int XC = BCOLS + 2;
    constexpr int NCOLF = BCOLS / 16, NCOF = CO / 16, NCC = CI / 32;
    constexpr int CPU8 = CI / 8;
    __shared__ u16 sx[5 * XC * CI];

    int bid = blockIdx.x;
    constexpr int NBY = HI / 4, NTX = WI / BCOLS;
    const int tx = bid % NTX; bid /= NTX;
    const int by = bid % NBY; const int n = bid / NBY;
    const int q0 = by * 4, r0 = tx * BCOLS;
    const int tid = threadIdx.x, w = tid >> 6, lane = tid & 63;
    const int l15 = lane & 15, l4 = lane >> 4;

    // ---- stage x tile rows [q0+RY-1 .. q0+RY+3], cols [r0-1 .. r0+BCOLS] ----
    const int qb = q0 + RY - 1;
    for (int u = tid; u < 5 * XC * CPU8; u += 256) {
        int c8 = u % CPU8; int t2 = u / CPU8;
        int xc = t2 % XC; int r = t2 / XC;
        int iy = qb + r, ix = r0 - 1 + xc;
        uint4 v = {0, 0, 0, 0};
        if (iy >= 0 && iy < HI && ix >= 0 && ix < WI)
            v = *(const uint4*)&xin[(((size_t)n * HI + iy) * WI + ix) * CI + c8 * 8];
        int byte = ((r * XC + xc) * CI + c8 * 8) * 2;
        byte ^= (xc & 7) << 4;
        *(uint4*)&sx[byte >> 1] = v;
    }
    __syncthreads();

    f32x4 acc[2][NCOLF][NCOF];
    #pragma unroll
    for (int rx = 0; rx < 2; ++rx)
        #pragma unroll
        for (int pf = 0; pf < NCOLF; ++pf)
            #pragma unroll
            for (int cf = 0; cf < NCOF; ++cf) {
                float bv = (MODE == 1) ? (l15 < 3 ? bias[l15] : 0.f) : bias[cf * 16 + l15];
                acc[rx][pf][cf] = (f32x4){bv, bv, bv, bv};
            }

    #pragma unroll
    for (int rx = 0; rx < 2; ++rx) {
        #pragma unroll 2
        for (int tap = 0; tap < 4; ++tap) {
            const int a_ = tap >> 1, b_ = tap & 1;
            const int s = (RY * 2 + rx) * 4 + tap;
            const int r = w + 1 - a_;
            #pragma unroll
            for (int cc = 0; cc < NCC; ++cc) {
                bf16x8 b[NCOF];
                #pragma unroll
                for (int cf = 0; cf < NCOF; ++cf)
                    b[cf] = *(const bf16x8*)&wt[((size_t)(s * CO + cf * 16 + l15)) * CI + cc * 32 + l4 * 8];
                bf16x8 a[NCOLF];
                #pragma unroll
                for (int pf = 0; pf < NCOLF; ++pf) {
                    int xc = pf * 16 + l15 + rx - b_ + 1;
                    int byte = ((r * XC + xc) * CI + cc * 32 + l4 * 8) * 2;
                    byte ^= (xc & 7) << 4;
                    a[pf] = *(const bf16x8*)&sx[byte >> 1];
                }
                #pragma unroll
                for (int pf = 0; pf < NCOLF; ++pf)
                    #pragma unroll
                    for (int cf = 0; cf < NCOF; ++cf)
                        acc[rx][pf][cf] = __builtin_amdgcn_mfma_f32_16x16x32_bf16(
                            a[pf], b[cf], acc[rx][pf][cf], 0, 0, 0);
            }
        }
    }

    const int oy = 2 * (q0 + w) + RY;
    if (MODE == 0) {
        u16* out = (u16*)outp;
        #pragma unroll
        for (int rx = 0; rx < 2; ++rx)
            #pragma unroll
            for (int pf = 0; pf < NCOLF; ++pf)
                #pragma unroll
                for (int cf = 0; cf < NCOF; ++cf)
                    #pragma unroll
                    for (int rg = 0; rg < 4; ++rg) {
                        int ox = 2 * (r0 + pf * 16 + l4 * 4 + rg) + rx;
                        float v = fmaxf(acc[rx][pf][cf][rg], 0.f);
                        out[(((size_t)n * HO + oy) * WO + ox) * CO + cf * 16 + l15] = f2b(v);
                    }
    } else {
        float* out = (float*)outp;
        const int co = l15;
        float lsum = 0.f;
        #pragma unroll
        for (int rx = 0; rx < 2; ++rx)
            #pragma unroll
            for (int pf = 0; pf < NCOLF; ++pf)
                #pragma unroll
                for (int rg = 0; rg < 4; ++rg) {
                    if (co < 3) {
                        int ox = 2 * (r0 + pf * 16 + l4 * 4 + rg) + rx;
                        size_t oi = (((size_t)n * 3 + co) * HO + oy) * WO + ox;
                        float sg = 1.f / (1.f + __expf(-acc[rx][pf][0][rg]));
                        out[oi] = sg;
                        float d = sg - ref[oi];
                        lsum = fmaf(d, d, lsum);
                    }
                }
        #pragma unroll
        for (int off = 32; off; off >>= 1) lsum += __shfl_down(lsum, off, 64);
        if (lane == 0) atomicAdd(&buckets[blockIdx.x & 255], lsum);
    }
}

// ---------------- fused VQ on NHWC bf16 z ----------------
__global__ void vq_kernel(const u16* __restrict__ z, const float* __restrict__ emb,
                          const float* __restrict__ e2, u16* __restrict__ zq,
                          float* __restrict__ vq_accum) {
    __shared__ float se[NEMB * LAT];   // 64 KB
    int tid = threadIdx.x;             // 128
    for (int i = tid; i < NEMB * LAT / 4; i += 128)
        ((float4*)se)[i] = ((const float4*)emb)[i];
    __syncthreads();

    int g = blockIdx.x * 128 + tid;    // 0..32767
    const u16* zp = z + (size_t)g * LAT;

    float zv[LAT], m2z[LAT];
    #pragma unroll
    for (int q = 0; q < 4; ++q) {
        V16 v; v.u = *(const uint4*)&zp[q * 8];
        #pragma unroll
        for (int j = 0; j < 8; ++j) {
            float f = b2f(v.s[j]);
            zv[q * 8 + j] = f; m2z[q * 8 + j] = -2.f * f;
        }
    }

    const float4* se4 = (const float4*)se;
    float best = 1e30f; int bk = 0;
    for (int k = 0; k < NEMB; ++k) {
        float d = e2[k];
        #pragma unroll
        for (int j = 0; j < 8; ++j) {
            float4 e4 = se4[k * 8 + j];
            d = fmaf(m2z[4 * j + 0], e4.x, d);
            d = fmaf(m2z[4 * j + 1], e4.y, d);
            d = fmaf(m2z[4 * j + 2], e4.z, d);
            d = fmaf(m2z[4 * j + 3], e4.w, d);
        }
        if (d < best) { best = d; bk = k; }   // strict < == first-index tie rule
    }

    float local = 0.f;
    u16* zqp = zq + (size_t)g * LAT;
    #pragma unroll
    for (int q = 0; q < 4; ++q) {
        V16 o;
        #pragma unroll
        for (int j = 0; j < 8; ++j) {
            float e = se[bk * LAT + q * 8 + j];
            float dd = e - zv[q * 8 + j];
            local = fmaf(dd, dd, local);
            o.s[j] = f2b(e);
        }
        *(uint4*)&zqp[q * 8] = o.u;
    }
    #pragma unroll
    for (int off = 32; off; off >>= 1) local += __shfl_down(local, off, 64);
    if ((tid & 63) == 0) atomicAdd(vq_accum, local);
}

__global__ void finalize_kernel(const float* __restrict__ accum, float* __restrict__ out,
                                int out_size) {
    int tid = threadIdx.x;  // 256
    float v = accum[tid];
    #pragma unroll
    for (int off = 32; off; off >>= 1) v += __shfl_down(v, off, 64);
    __shared__ float s[4];
    if ((tid & 63) == 0) s[tid >> 6] = v;
    __syncthreads();
    if (tid == 0) {
        float tot = s[0] + s[1] + s[2] + s[3];
        out[out_size - 2] = tot / 6291456.f;                 // recon_loss
        out[out_size - 1] = 1.25f * accum[256] / 1048576.f;  // vq_loss
    }
}

extern "C" void kernel_launch(void* const* d_in, const int* in_sizes, int n_in,
                              void* d_out, int out_size, void* d_ws, size_t ws_size,
                              hipStream_t stream) {
    const float* x   = (const float*)d_in[0];
    const float* w1  = (const float*)d_in[1];
    const float* b1  = (const float*)d_in[2];
    const float* w2  = (const float*)d_in[3];
    const float* b2  = (const float*)d_in[4];
    const float* w3  = (const float*)d_in[5];
    const float* b3  = (const float*)d_in[6];
    const float* emb = (const float*)d_in[7];
    const float* d1  = (const float*)d_in[8];
    const float* db1 = (const float*)d_in[9];
    const float* d2  = (const float*)d_in[10];
    const float* db2 = (const float*)d_in[11];
    const float* d3  = (const float*)d_in[12];
    const float* db3 = (const float*)d_in[13];

    char* ws = (char*)d_ws;
    u16* h1  = (u16*)(ws + OFF_H1);    // also g2
    u16* h2  = (u16*)(ws + OFF_H2);    // also g1
    u16* zb  = (u16*)(ws + OFF_Z);
    u16* zqb = (u16*)(ws + OFF_ZQ);
    u16* w2t = (u16*)(ws + OFF_W2T);
    u16* w3t = (u16*)(ws + OFF_W3T);
    u16* d1t = (u16*)(ws + OFF_D1T);
    u16* d2t = (u16*)(ws + OFF_D2T);
    u16* d3t = (u16*)(ws + OFF_D3T);
    float* acc = (float*)(ws + OFF_ACC);
    float* e2  = (float*)(ws + OFF_E2);
    float* out = (float*)d_out;

    init_kernel<<<2, 256, 0, stream>>>(emb, acc, e2);
    wt_conv_k  <<<128, 256, 0, stream>>>(w2, w2t, 64, 32);
    wt_conv_k  <<<128, 256, 0, stream>>>(w3, w3t, 32, 64);
    wt_deconv_k<<<128, 256, 0, stream>>>(d1, d1t, 64, 32);
    wt_deconv_k<<<128, 256, 0, stream>>>(d2, d2t, 32, 64);
    wt_d3_k    <<<32, 256, 0, stream>>>(d3, d3t);

    // encoder
    conv1_direct<<<2048, 256, 0, stream>>>(x, w1, b1, h1);
    mfma_conv<32, 64, 64, 64, true ><<<1024, 256, 0, stream>>>(h1, w2t, b2, h2);
    mfma_conv<64, 32, 32, 32, false><<<512, 256, 0, stream>>>(h2, w3t, b3, zb);

    // vector quantization
    vq_kernel<<<256, 128, 0, stream>>>(zb, emb, e2, zqb, acc + 256);

    // decoder (g1 reuses h2 space, g2 reuses h1 space)
    u16* g1 = h2; u16* g2 = h1;
    mfma_deconv<32, 64, 16, 16, 0, 0><<<512, 256, 0, stream>>>(zqb, d1t, db1, g1, nullptr, nullptr);
    mfma_deconv<32, 64, 16, 16, 1, 0><<<512, 256, 0, stream>>>(zqb, d1t, db1, g1, nullptr, nullptr);
    mfma_deconv<64, 32, 32, 32, 0, 0><<<1024, 256, 0, stream>>>(g1, d2t, db2, g2, nullptr, nullptr);
    mfma_deconv<64, 32, 32, 32, 1, 0><<<1024, 256, 0, stream>>>(g1, d2t, db2, g2, nullptr, nullptr);
    mfma_deconv<32, 16, 64, 64, 0, 1><<<4096, 256, 0, stream>>>(g2, d3t, db3, out, x, acc);
    mfma_deconv<32, 16, 64, 64, 1, 1><<<4096, 256, 0, stream>>>(g2, d3t, db3, out, x, acc);

    finalize_kernel<<<1, 256, 0, stream>>>(acc, out, out_size);
}

// Round 4
// 266.123 us; speedup vs baseline: 23.7262x; 1.4867x over previous
//
#include <hip/hip_runtime.h>
#include <math.h>

#define NEMB 512
#define LAT 32

typedef unsigned short u16;
typedef __attribute__((ext_vector_type(8))) short bf16x8;   // 8 bf16 in 4 VGPRs
typedef __attribute__((ext_vector_type(4))) float f32x4;

__device__ __forceinline__ u16 f2b(float f) {               // fp32 -> bf16 RTNE
    unsigned u = __builtin_bit_cast(unsigned, f);
    return (u16)((u + 0x7fffu + ((u >> 16) & 1u)) >> 16);
}
__device__ __forceinline__ float b2f(u16 h) {
    unsigned u = ((unsigned)h) << 16;
    return __builtin_bit_cast(float, u);
}

union V16 { uint4 u; u16 s[8]; };

// ---------------- workspace layout (BYTES) ----------------
static const size_t OFF_H1  = 0;          // h1 [128,64,64,32] bf16 (later g2)
static const size_t OFF_H2  = 33554432;   // h2 [128,32,32,64] bf16 (later g1)
static const size_t OFF_Z   = 50331648;   // z  [128,16,16,32] bf16
static const size_t OFF_ZQ  = 52428800;   // zq [128,16,16,32] bf16
static const size_t OFF_W2T = 54525952;   // [16][64][32] bf16
static const size_t OFF_W3T = 54591488;   // [16][32][64] bf16
static const size_t OFF_D1T = 54657024;   // [16][64][32] bf16
static const size_t OFF_D2T = 54722560;   // [16][32][64] bf16
static const size_t OFF_D3T = 54788096;   // [16][16][32] bf16 (co padded 3->16)
static const size_t OFF_ACC = 54804480;   // f32: [0..255] recon buckets, [256] vq sum
static const size_t OFF_E2  = 54806528;   // f32: per-code ||e||^2

// =================================================================
// prep: all weight transforms + e2 + accumulator zeroing in ONE kernel
// =================================================================
__global__ __launch_bounds__(256)
void prep_kernel(const float* __restrict__ w2, const float* __restrict__ w3,
                 const float* __restrict__ d1, const float* __restrict__ d2,
                 const float* __restrict__ d3, const float* __restrict__ emb,
                 u16* __restrict__ w2t, u16* __restrict__ w3t, u16* __restrict__ d1t,
                 u16* __restrict__ d2t, u16* __restrict__ d3t,
                 float* __restrict__ accum, float* __restrict__ e2) {
    int t = blockIdx.x * 256 + threadIdx.x;
    if (t < 32768) {                       // w2: conv, CO=64 CI=32 -> [tau][co][ci]
        int ci = t & 31; int t2 = t >> 5; int co = t2 & 63; int tau = t2 >> 6;
        w2t[t] = f2b(w2[((size_t)co * 32 + ci) * 16 + tau]);
    } else if (t < 65536) {                // w3: conv, CO=32 CI=64
        int u = t - 32768;
        int ci = u & 63; int t2 = u >> 6; int co = t2 & 31; int tau = t2 >> 5;
        w3t[u] = f2b(w3[((size_t)co * 64 + ci) * 16 + tau]);
    } else if (t < 98304) {                // d1: deconv, CO=64 CI=32 -> [s][co][ci]
        int u = t - 65536;
        int ci = u & 31; int t2 = u >> 5; int co = t2 & 63; int s = t2 >> 6;
        int ry = (s >> 3) & 1, rx = (s >> 2) & 1, a = (s >> 1) & 1, b = s & 1;
        int ky = ((ry + 1) & 1) + 2 * a, kx = ((rx + 1) & 1) + 2 * b;
        d1t[u] = f2b(d1[((size_t)ci * 64 + co) * 16 + ky * 4 + kx]);
    } else if (t < 131072) {               // d2: deconv, CO=32 CI=64
        int u = t - 98304;
        int ci = u & 63; int t2 = u >> 6; int co = t2 & 31; int s = t2 >> 5;
        int ry = (s >> 3) & 1, rx = (s >> 2) & 1, a = (s >> 1) & 1, b = s & 1;
        int ky = ((ry + 1) & 1) + 2 * a, kx = ((rx + 1) & 1) + 2 * b;
        d2t[u] = f2b(d2[((size_t)ci * 32 + co) * 16 + ky * 4 + kx]);
    } else if (t < 139264) {               // d3: CO padded 3->16, CI=32
        int u = t - 131072;
        int ci = u & 31; int co = (u >> 5) & 15; int s = u >> 9;
        int ry = (s >> 3) & 1, rx = (s >> 2) & 1, a = (s >> 1) & 1, b = s & 1;
        int ky = ((ry + 1) & 1) + 2 * a, kx = ((rx + 1) & 1) + 2 * b;
        d3t[u] = (co < 3) ? f2b(d3[((size_t)ci * 3 + co) * 16 + ky * 4 + kx]) : (u16)0;
    } else if (t < 139776) {               // e2
        int u = t - 139264;
        float s = 0.f;
        #pragma unroll
        for (int c = 0; c < LAT; ++c) { float e = emb[u * LAT + c]; s = fmaf(e, e, s); }
        e2[u] = s;
    } else if (t < 140096) {               // zero accumulators
        accum[t - 139776] = 0.f;
    }
}

// =================================================================
// conv1 direct: x NCHW f32 [128,3,128,128] -> h1 NHWC bf16 [128,64,64,32]
// =================================================================
__global__ __launch_bounds__(256)
void conv1_direct(const float* __restrict__ x, const float* __restrict__ w1,
                  const float* __restrict__ b1, u16* __restrict__ h1) {
    __shared__ float sx[3 * 34 * 35];
    __shared__ float sw[3 * 16 * 32];   // [ci][kykx][co]
    int bid = blockIdx.x;
    const int tx = bid % 4; bid /= 4;
    const int ty = bid % 4; const int n = bid / 4;
    const int tid = threadIdx.x, tr = tid >> 4, tc = tid & 15;

    for (int u = tid; u < 3 * 34 * 34; u += 256) {
        int c = u / 1156; int rem = u % 1156; int r = rem / 34; int col = rem % 34;
        int iy = ty * 32 - 1 + r, ix = tx * 32 - 1 + col;
        float v = 0.f;
        if (iy >= 0 && iy < 128 && ix >= 0 && ix < 128)
            v = x[(((size_t)n * 3 + c) * 128 + iy) * 128 + ix];
        sx[(c * 34 + r) * 35 + col] = v;
    }
    for (int l = tid; l < 1536; l += 256) {
        int co = l & 31, kykx = (l >> 5) & 15, ci = l >> 9;
        sw[l] = w1[((size_t)co * 3 + ci) * 16 + kykx];
    }
    __syncthreads();

    float acc[32];
    #pragma unroll
    for (int c = 0; c < 32; ++c) acc[c] = b1[c];

    for (int ci = 0; ci < 3; ++ci) {
        float tv[16];
        #pragma unroll
        for (int ky = 0; ky < 4; ++ky)
            #pragma unroll
            for (int kx = 0; kx < 4; ++kx)
                tv[ky * 4 + kx] = sx[(ci * 34 + 2 * tr + ky) * 35 + 2 * tc + kx];
        #pragma unroll
        for (int kk = 0; kk < 16; ++kk) {
            float t = tv[kk];
            const float4* wp = (const float4*)&sw[(ci * 16 + kk) * 32];
            #pragma unroll
            for (int q = 0; q < 8; ++q) {
                float4 wv = wp[q];
                acc[q * 4 + 0] = fmaf(t, wv.x, acc[q * 4 + 0]);
                acc[q * 4 + 1] = fmaf(t, wv.y, acc[q * 4 + 1]);
                acc[q * 4 + 2] = fmaf(t, wv.z, acc[q * 4 + 2]);
                acc[q * 4 + 3] = fmaf(t, wv.w, acc[q * 4 + 3]);
            }
        }
    }
    const int oy = ty * 16 + tr, ox = tx * 16 + tc;
    size_t base = (((size_t)n * 64 + oy) * 64 + ox) * 32;
    #pragma unroll
    for (int q = 0; q < 4; ++q) {
        V16 o;
        #pragma unroll
        for (int j = 0; j < 8; ++j) o.s[j] = f2b(fmaxf(acc[q * 8 + j], 0.f));
        *(uint4*)&h1[base + q * 8] = o.u;
    }
}

// =================================================================
// MFMA conv k4s2: NHWC bf16 in/out.
// =================================================================
template <int CI, int CO, int HI, int WI, bool RELU>
__global__ __launch_bounds__(256)
void mfma_conv(const u16* __restrict__ xin, const u16* __restrict__ wt,
               const float* __restrict__ bias, u16* __restrict__ out) {
    constexpr int HO = HI / 2, WO = WI / 2;
    constexpr int BCOLS = (WO < 32) ? WO : 32;
    constexpr int XC = 2 * BCOLS + 2;
    constexpr int NCOLF = BCOLS / 16, NCOF = CO / 16, NCC = CI / 32;
    constexpr int CPU8 = CI / 8;
    __shared__ u16 sx[10 * XC * CI];

    int bid = blockIdx.x;
    constexpr int NBY = HO / 4, NTX = WO / BCOLS;
    const int tx = bid % NTX; bid /= NTX;
    const int by = bid % NBY; const int n = bid / NBY;
    const int oy0 = by * 4, ox0 = tx * BCOLS;
    const int tid = threadIdx.x, w = tid >> 6, lane = tid & 63;
    const int l15 = lane & 15, l4 = lane >> 4;

    const int iyb = 2 * oy0 - 1, ixb = 2 * ox0 - 1;
    for (int u = tid; u < 10 * XC * CPU8; u += 256) {
        int c8 = u % CPU8; int t2 = u / CPU8;
        int xc = t2 % XC; int r = t2 / XC;
        int iy = iyb + r, ix = ixb + xc;
        uint4 v = {0, 0, 0, 0};
        if (iy >= 0 && iy < HI && ix >= 0 && ix < WI)
            v = *(const uint4*)&xin[(((size_t)n * HI + iy) * WI + ix) * CI + c8 * 8];
        int byte = ((r * XC + xc) * CI + c8 * 8) * 2;
        byte ^= ((xc >> 1) & 7) << 4;
        *(uint4*)&sx[byte >> 1] = v;
    }
    __syncthreads();

    f32x4 acc[NCOLF][NCOF];
    #pragma unroll
    for (int pf = 0; pf < NCOLF; ++pf)
        #pragma unroll
        for (int cf = 0; cf < NCOF; ++cf) {
            float bv = bias[cf * 16 + l15];
            acc[pf][cf] = (f32x4){bv, bv, bv, bv};
        }

    #pragma unroll 2
    for (int tau = 0; tau < 16; ++tau) {
        const int ky = tau >> 2, kx = tau & 3;
        const int r = 2 * w + ky;
        #pragma unroll
        for (int cc = 0; cc < NCC; ++cc) {
            bf16x8 b[NCOF];
            #pragma unroll
            for (int cf = 0; cf < NCOF; ++cf)
                b[cf] = *(const bf16x8*)&wt[((size_t)(tau * CO + cf * 16 + l15)) * CI + cc * 32 + l4 * 8];
            bf16x8 a[NCOLF];
            #pragma unroll
            for (int pf = 0; pf < NCOLF; ++pf) {
                int xc = 2 * (pf * 16 + l15) + kx;
                int byte = ((r * XC + xc) * CI + cc * 32 + l4 * 8) * 2;
                byte ^= ((xc >> 1) & 7) << 4;
                a[pf] = *(const bf16x8*)&sx[byte >> 1];
            }
            #pragma unroll
            for (int pf = 0; pf < NCOLF; ++pf)
                #pragma unroll
                for (int cf = 0; cf < NCOF; ++cf)
                    acc[pf][cf] = __builtin_amdgcn_mfma_f32_16x16x32_bf16(
                        a[pf], b[cf], acc[pf][cf], 0, 0, 0);
        }
    }

    const int oy = oy0 + w;
    #pragma unroll
    for (int pf = 0; pf < NCOLF; ++pf)
        #pragma unroll
        for (int cf = 0; cf < NCOF; ++cf)
            #pragma unroll
            for (int rg = 0; rg < 4; ++rg) {
                int ox = ox0 + pf * 16 + l4 * 4 + rg;
                float v = acc[pf][cf][rg];
                if (RELU) v = fmaxf(v, 0.f);
                out[(((size_t)n * HO + oy) * WO + ox) * CO + cf * 16 + l15] = f2b(v);
            }
}

// =================================================================
// MFMA deconv k4s2, phase ry = blockIdx.y (output rows oy = 2q + ry).
// MODE 0: relu -> bf16 NHWC.  MODE 1: sigmoid -> f32 NCHW (co<3) + loss.
// =================================================================
template <int CI, int CO, int HI, int WI, int MODE>
__global__ __launch_bounds__(256)
void mfma_deconv(const u16* __restrict__ xin, const u16* __restrict__ wt,
                 const float* __restrict__ bias, void* __restrict__ outp,
                 const float* __restrict__ ref, float* __restrict__ buckets) {
    constexpr int HO = 2 * HI, WO = 2 * WI;
    constexpr int BCOLS = (WI < 32) ? WI : 32;
    constexpr int XC = BCOLS + 2;
    constexpr int NCOLF = BCOLS / 16, NCOF = CO / 16, NCC = CI / 32;
    constexpr int CPU8 = CI / 8;
    __shared__ u16 sx[5 * XC * CI];

    const int ry = blockIdx.y;
    int bid = blockIdx.x;
    constexpr int NBY = HI / 4, NTX = WI / BCOLS;
    const int tx = bid % NTX; bid /= NTX;
    const int by = bid % NBY; const int n = bid / NBY;
    const int q0 = by * 4, r0 = tx * BCOLS;
    const int tid = threadIdx.x, w = tid >> 6, lane = tid & 63;
    const int l15 = lane & 15, l4 = lane >> 4;
    const u16* wts = wt + (size_t)(ry * 8) * CO * CI;

    const int qb = q0 + ry - 1;
    for (int u = tid; u < 5 * XC * CPU8; u += 256) {
        int c8 = u % CPU8; int t2 = u / CPU8;
        int xc = t2 % XC; int r = t2 / XC;
        int iy = qb + r, ix = r0 - 1 + xc;
        uint4 v = {0, 0, 0, 0};
        if (iy >= 0 && iy < HI && ix >= 0 && ix < WI)
            v = *(const uint4*)&xin[(((size_t)n * HI + iy) * WI + ix) * CI + c8 * 8];
        int byte = ((r * XC + xc) * CI + c8 * 8) * 2;
        byte ^= (xc & 7) << 4;
        *(uint4*)&sx[byte >> 1] = v;
    }
    __syncthreads();

    f32x4 acc[2][NCOLF][NCOF];
    #pragma unroll
    for (int rx = 0; rx < 2; ++rx)
        #pragma unroll
        for (int pf = 0; pf < NCOLF; ++pf)
            #pragma unroll
            for (int cf = 0; cf < NCOF; ++cf) {
                float bv = (MODE == 1) ? (l15 < 3 ? bias[l15] : 0.f) : bias[cf * 16 + l15];
                acc[rx][pf][cf] = (f32x4){bv, bv, bv, bv};
            }

    #pragma unroll
    for (int rx = 0; rx < 2; ++rx) {
        #pragma unroll 2
        for (int tap = 0; tap < 4; ++tap) {
            const int a_ = tap >> 1, b_ = tap & 1;
            const int r = w + 1 - a_;
            #pragma unroll
            for (int cc = 0; cc < NCC; ++cc) {
                bf16x8 b[NCOF];
                #pragma unroll
                for (int cf = 0; cf < NCOF; ++cf)
                    b[cf] = *(const bf16x8*)&wts[((size_t)((rx * 4 + tap) * CO + cf * 16 + l15)) * CI + cc * 32 + l4 * 8];
                bf16x8 a[NCOLF];
                #pragma unroll
                for (int pf = 0; pf < NCOLF; ++pf) {
                    int xc = pf * 16 + l15 + rx - b_ + 1;
                    int byte = ((r * XC + xc) * CI + cc * 32 + l4 * 8) * 2;
                    byte ^= (xc & 7) << 4;
                    a[pf] = *(const bf16x8*)&sx[byte >> 1];
                }
                #pragma unroll
                for (int pf = 0; pf < NCOLF; ++pf)
                    #pragma unroll
                    for (int cf = 0; cf < NCOF; ++cf)
                        acc[rx][pf][cf] = __builtin_amdgcn_mfma_f32_16x16x32_bf16(
                            a[pf], b[cf], acc[rx][pf][cf], 0, 0, 0);
            }
        }
    }

    const int oy = 2 * (q0 + w) + ry;
    if (MODE == 0) {
        u16* out = (u16*)outp;
        #pragma unroll
        for (int rx = 0; rx < 2; ++rx)
            #pragma unroll
            for (int pf = 0; pf < NCOLF; ++pf)
                #pragma unroll
                for (int cf = 0; cf < NCOF; ++cf)
                    #pragma unroll
                    for (int rg = 0; rg < 4; ++rg) {
                        int ox = 2 * (r0 + pf * 16 + l4 * 4 + rg) + rx;
                        float v = fmaxf(acc[rx][pf][cf][rg], 0.f);
                        out[(((size_t)n * HO + oy) * WO + ox) * CO + cf * 16 + l15] = f2b(v);
                    }
    } else {
        float* out = (float*)outp;
        const int co = l15;
        float lsum = 0.f;
        #pragma unroll
        for (int rx = 0; rx < 2; ++rx)
            #pragma unroll
            for (int pf = 0; pf < NCOLF; ++pf)
                #pragma unroll
                for (int rg = 0; rg < 4; ++rg) {
                    if (co < 3) {
                        int ox = 2 * (r0 + pf * 16 + l4 * 4 + rg) + rx;
                        size_t oi = (((size_t)n * 3 + co) * HO + oy) * WO + ox;
                        float sg = 1.f / (1.f + __expf(-acc[rx][pf][0][rg]));
                        out[oi] = sg;
                        float d = sg - ref[oi];
                        lsum = fmaf(d, d, lsum);
                    }
                }
        #pragma unroll
        for (int off = 32; off; off >>= 1) lsum += __shfl_down(lsum, off, 64);
        if (lane == 0) atomicAdd(&buckets[blockIdx.x & 255], lsum);
    }
}

// =================================================================
// MFMA VQ: distances via z @ emb^T (16x16x32 bf16), wave-parallel argmin.
// One wave per 16 z-rows; codebook staged swizzled in LDS per block.
// =================================================================
__global__ __launch_bounds__(256)
void vq_mfma(const u16* __restrict__ z, const float* __restrict__ emb,
             const float* __restrict__ e2g, u16* __restrict__ zq,
             float* __restrict__ vq_accum) {
    __shared__ u16 semb[NEMB * LAT];   // 32 KB, XOR-swizzled [code][k]
    __shared__ float se2[NEMB];        // 2 KB
    const int tid = threadIdx.x;

    for (int u = tid; u < 2048; u += 256) {
        int code = u >> 2, seg = u & 3;
        const float4* ep = (const float4*)&emb[code * 32 + seg * 8];
        float4 e0 = ep[0], e1 = ep[1];
        V16 o;
        o.s[0] = f2b(e0.x); o.s[1] = f2b(e0.y); o.s[2] = f2b(e0.z); o.s[3] = f2b(e0.w);
        o.s[4] = f2b(e1.x); o.s[5] = f2b(e1.y); o.s[6] = f2b(e1.z); o.s[7] = f2b(e1.w);
        int byte = (code * 64 + seg * 16) ^ ((code & 7) << 4);
        *(uint4*)((char*)semb + byte) = o.u;
    }
    if (tid < NEMB) se2[tid] = e2g[tid];
    __syncthreads();

    const int w = tid >> 6, lane = tid & 63;
    const int l15 = lane & 15, l4 = lane >> 4;
    const int rowbase = blockIdx.x * 64 + w * 16;

    // A fragment: row = l15 (z vector), k-run = l4*8. z rows are 64B contiguous.
    bf16x8 a = *(const bf16x8*)&z[(size_t)(rowbase + l15) * LAT + l4 * 8];

    float best[4] = {1e30f, 1e30f, 1e30f, 1e30f};
    int   bidx[4] = {0, 0, 0, 0};
    #pragma unroll
    for (int f = 0; f < 32; ++f) {
        int byteb = ((f * 16 + l15) * 64 + l4 * 16) ^ ((l15 & 7) << 4);
        bf16x8 bfrag = *(const bf16x8*)((const char*)semb + byteb);
        f32x4 s = {0.f, 0.f, 0.f, 0.f};
        s = __builtin_amdgcn_mfma_f32_16x16x32_bf16(a, bfrag, s, 0, 0, 0);
        float e2c = se2[f * 16 + l15];
        int cidx = f * 16 + l15;
        #pragma unroll
        for (int j = 0; j < 4; ++j) {
            float d = fmaf(s[j], -2.f, e2c);   // d = e2 - 2 z.e (+ const z2 omitted)
            bool lt = d < best[j];             // strict <: keeps smallest code index
            best[j] = lt ? d : best[j];
            bidx[j] = lt ? cidx : bidx[j];
        }
    }
    // butterfly min+first-index over the 16 code-lanes (masks < 16 stay in group)
    #pragma unroll
    for (int m = 1; m < 16; m <<= 1) {
        #pragma unroll
        for (int j = 0; j < 4; ++j) {
            float ob = __shfl_xor(best[j], m, 64);
            int   oi = __shfl_xor(bidx[j], m, 64);
            bool take = (ob < best[j]) || (ob == best[j] && oi < bidx[j]);
            best[j] = take ? ob : best[j];
            bidx[j] = take ? oi : bidx[j];
        }
    }
    // gather: lane handles local row r = lane>>2 (r>>2 == own l4), seg = lane&3
    const int r = lane >> 2;
    const int j0 = r & 3;
    int k = (j0 == 0) ? bidx[0] : (j0 == 1) ? bidx[1] : (j0 == 2) ? bidx[2] : bidx[3];
    const int seg = lane & 3;
    const float4* ep = (const float4*)&emb[k * LAT + seg * 8];
    float4 e0 = ep[0], e1 = ep[1];
    float ev[8] = {e0.x, e0.y, e0.z, e0.w, e1.x, e1.y, e1.z, e1.w};
    size_t zoff = (size_t)(rowbase + r) * LAT + seg * 8;
    V16 zr; zr.u = *(const uint4*)&z[zoff];
    V16 o;
    float local = 0.f;
    #pragma unroll
    for (int jj = 0; jj < 8; ++jj) {
        float dd = ev[jj] - b2f(zr.s[jj]);
        local = fmaf(dd, dd, local);
        o.s[jj] = f2b(ev[jj]);
    }
    *(uint4*)&zq[zoff] = o.u;
    #pragma unroll
    for (int off = 32; off; off >>= 1) local += __shfl_down(local, off, 64);
    if (lane == 0) atomicAdd(vq_accum, local);
}

__global__ void finalize_kernel(const float* __restrict__ accum, float* __restrict__ out,
                                int out_size) {
    int tid = threadIdx.x;  // 256
    float v = accum[tid];
    #pragma unroll
    for (int off = 32; off; off >>= 1) v += __shfl_down(v, off, 64);
    __shared__ float s[4];
    if ((tid & 63) == 0) s[tid >> 6] = v;
    __syncthreads();
    if (tid == 0) {
        float tot = s[0] + s[1] + s[2] + s[3];
        out[out_size - 2] = tot / 6291456.f;                 // recon_loss
        out[out_size - 1] = 1.25f * accum[256] / 1048576.f;  // vq_loss
    }
}

extern "C" void kernel_launch(void* const* d_in, const int* in_sizes, int n_in,
                              void* d_out, int out_size, void* d_ws, size_t ws_size,
                              hipStream_t stream) {
    const float* x   = (const float*)d_in[0];
    const float* w1  = (const float*)d_in[1];
    const float* b1  = (const float*)d_in[2];
    const float* w2  = (const float*)d_in[3];
    const float* b2  = (const float*)d_in[4];
    const float* w3  = (const float*)d_in[5];
    const float* b3  = (const float*)d_in[6];
    const float* emb = (const float*)d_in[7];
    const float* d1  = (const float*)d_in[8];
    const float* db1 = (const float*)d_in[9];
    const float* d2  = (const float*)d_in[10];
    const float* db2 = (const float*)d_in[11];
    const float* d3  = (const float*)d_in[12];
    const float* db3 = (const float*)d_in[13];

    char* ws = (char*)d_ws;
    u16* h1  = (u16*)(ws + OFF_H1);    // also g2
    u16* h2  = (u16*)(ws + OFF_H2);    // also g1
    u16* zb  = (u16*)(ws + OFF_Z);
    u16* zqb = (u16*)(ws + OFF_ZQ);
    u16* w2t = (u16*)(ws + OFF_W2T);
    u16* w3t = (u16*)(ws + OFF_W3T);
    u16* d1t = (u16*)(ws + OFF_D1T);
    u16* d2t = (u16*)(ws + OFF_D2T);
    u16* d3t = (u16*)(ws + OFF_D3T);
    float* acc = (float*)(ws + OFF_ACC);
    float* e2  = (float*)(ws + OFF_E2);
    float* out = (float*)d_out;

    prep_kernel<<<548, 256, 0, stream>>>(w2, w3, d1, d2, d3, emb,
                                         w2t, w3t, d1t, d2t, d3t, acc, e2);

    // encoder
    conv1_direct<<<2048, 256, 0, stream>>>(x, w1, b1, h1);
    mfma_conv<32, 64, 64, 64, true ><<<1024, 256, 0, stream>>>(h1, w2t, b2, h2);
    mfma_conv<64, 32, 32, 32, false><<<512, 256, 0, stream>>>(h2, w3t, b3, zb);

    // vector quantization
    vq_mfma<<<512, 256, 0, stream>>>(zb, emb, e2, zqb, acc + 256);

    // decoder (g1 reuses h2 space, g2 reuses h1 space)
    u16* g1 = h2; u16* g2 = h1;
    mfma_deconv<32, 64, 16, 16, 0><<<dim3(512, 2), 256, 0, stream>>>(zqb, d1t, db1, g1, nullptr, nullptr);
    mfma_deconv<64, 32, 32, 32, 0><<<dim3(1024, 2), 256, 0, stream>>>(g1, d2t, db2, g2, nullptr, nullptr);
    mfma_deconv<32, 16, 64, 64, 1><<<dim3(4096, 2), 256, 0, stream>>>(g2, d3t, db3, out, x, acc);

    finalize_kernel<<<1, 256, 0, stream>>>(acc, out, out_size);
}

// Round 5
// 237.503 us; speedup vs baseline: 26.5853x; 1.1205x over previous
//
#include <hip/hip_runtime.h>
#include <math.h>

#define NEMB 512
#define LAT 32

typedef unsigned short u16;
typedef __attribute__((ext_vector_type(8))) short bf16x8;   // 8 bf16 in 4 VGPRs
typedef __attribute__((ext_vector_type(4))) float f32x4;

__device__ __forceinline__ u16 f2b(float f) {               // fp32 -> bf16 RTNE
    unsigned u = __builtin_bit_cast(unsigned, f);
    return (u16)((u + 0x7fffu + ((u >> 16) & 1u)) >> 16);
}
__device__ __forceinline__ float b2f(u16 h) {
    unsigned u = ((unsigned)h) << 16;
    return __builtin_bit_cast(float, u);
}

union V16 { uint4 u; u16 s[8]; };

// ---------------- workspace layout (BYTES) ----------------
static const size_t OFF_H1  = 0;          // h1 [128,64,64,32] bf16 (later g2)
static const size_t OFF_H2  = 33554432;   // h2 [128,32,32,64] bf16 (later g1)
static const size_t OFF_Z   = 50331648;   // z  [128,16,16,32] bf16
static const size_t OFF_ZQ  = 52428800;   // zq [128,16,16,32] bf16
static const size_t OFF_W2T = 54525952;   // [16][64][32] bf16
static const size_t OFF_W3T = 54591488;   // [16][32][64] bf16
static const size_t OFF_D1T = 54657024;   // [16][64][32] bf16
static const size_t OFF_D2T = 54722560;   // [16][32][64] bf16
static const size_t OFF_ACC = 54804480;   // f32: [0..255] recon buckets, [256] vq sum
static const size_t OFF_E2  = 54806528;   // f32: per-code ||e||^2

// =================================================================
// prep: weight transforms + e2 + accumulator zeroing in ONE kernel
// =================================================================
__global__ __launch_bounds__(256)
void prep_kernel(const float* __restrict__ w2, const float* __restrict__ w3,
                 const float* __restrict__ d1, const float* __restrict__ d2,
                 const float* __restrict__ emb,
                 u16* __restrict__ w2t, u16* __restrict__ w3t, u16* __restrict__ d1t,
                 u16* __restrict__ d2t,
                 float* __restrict__ accum, float* __restrict__ e2) {
    int t = blockIdx.x * 256 + threadIdx.x;
    if (t < 32768) {                       // w2: conv, CO=64 CI=32 -> [tau][co][ci]
        int ci = t & 31; int t2 = t >> 5; int co = t2 & 63; int tau = t2 >> 6;
        w2t[t] = f2b(w2[((size_t)co * 32 + ci) * 16 + tau]);
    } else if (t < 65536) {                // w3: conv, CO=32 CI=64
        int u = t - 32768;
        int ci = u & 63; int t2 = u >> 6; int co = t2 & 31; int tau = t2 >> 5;
        w3t[u] = f2b(w3[((size_t)co * 64 + ci) * 16 + tau]);
    } else if (t < 98304) {                // d1: deconv, CO=64 CI=32 -> [s][co][ci]
        int u = t - 65536;
        int ci = u & 31; int t2 = u >> 5; int co = t2 & 63; int s = t2 >> 6;
        int ry = (s >> 3) & 1, rx = (s >> 2) & 1, a = (s >> 1) & 1, b = s & 1;
        int ky = ((ry + 1) & 1) + 2 * a, kx = ((rx + 1) & 1) + 2 * b;
        d1t[u] = f2b(d1[((size_t)ci * 64 + co) * 16 + ky * 4 + kx]);
    } else if (t < 131072) {               // d2: deconv, CO=32 CI=64
        int u = t - 98304;
        int ci = u & 63; int t2 = u >> 6; int co = t2 & 31; int s = t2 >> 5;
        int ry = (s >> 3) & 1, rx = (s >> 2) & 1, a = (s >> 1) & 1, b = s & 1;
        int ky = ((ry + 1) & 1) + 2 * a, kx = ((rx + 1) & 1) + 2 * b;
        d2t[u] = f2b(d2[((size_t)ci * 32 + co) * 16 + ky * 4 + kx]);
    } else if (t < 131584) {               // e2
        int u = t - 131072;
        float s = 0.f;
        #pragma unroll
        for (int c = 0; c < LAT; ++c) { float e = emb[u * LAT + c]; s = fmaf(e, e, s); }
        e2[u] = s;
    } else if (t < 131904) {               // zero accumulators
        accum[t - 131584] = 0.f;
    }
}

// =================================================================
// conv1 direct: x NCHW f32 [128,3,128,128] -> h1 NHWC bf16 [128,64,64,32]
// =================================================================
__global__ __launch_bounds__(256)
void conv1_direct(const float* __restrict__ x, const float* __restrict__ w1,
                  const float* __restrict__ b1, u16* __restrict__ h1) {
    __shared__ float sx[3 * 34 * 35];
    __shared__ float sw[3 * 16 * 32];   // [ci][kykx][co]
    int bid = blockIdx.x;
    const int tx = bid % 4; bid /= 4;
    const int ty = bid % 4; const int n = bid / 4;
    const int tid = threadIdx.x, tr = tid >> 4, tc = tid & 15;

    for (int u = tid; u < 3 * 34 * 34; u += 256) {
        int c = u / 1156; int rem = u % 1156; int r = rem / 34; int col = rem % 34;
        int iy = ty * 32 - 1 + r, ix = tx * 32 - 1 + col;
        float v = 0.f;
        if (iy >= 0 && iy < 128 && ix >= 0 && ix < 128)
            v = x[(((size_t)n * 3 + c) * 128 + iy) * 128 + ix];
        sx[(c * 34 + r) * 35 + col] = v;
    }
    for (int l = tid; l < 1536; l += 256) {
        int co = l & 31, kykx = (l >> 5) & 15, ci = l >> 9;
        sw[l] = w1[((size_t)co * 3 + ci) * 16 + kykx];
    }
    __syncthreads();

    float acc[32];
    #pragma unroll
    for (int c = 0; c < 32; ++c) acc[c] = b1[c];

    for (int ci = 0; ci < 3; ++ci) {
        float tv[16];
        #pragma unroll
        for (int ky = 0; ky < 4; ++ky)
            #pragma unroll
            for (int kx = 0; kx < 4; ++kx)
                tv[ky * 4 + kx] = sx[(ci * 34 + 2 * tr + ky) * 35 + 2 * tc + kx];
        #pragma unroll
        for (int kk = 0; kk < 16; ++kk) {
            float t = tv[kk];
            const float4* wp = (const float4*)&sw[(ci * 16 + kk) * 32];
            #pragma unroll
            for (int q = 0; q < 8; ++q) {
                float4 wv = wp[q];
                acc[q * 4 + 0] = fmaf(t, wv.x, acc[q * 4 + 0]);
                acc[q * 4 + 1] = fmaf(t, wv.y, acc[q * 4 + 1]);
                acc[q * 4 + 2] = fmaf(t, wv.z, acc[q * 4 + 2]);
                acc[q * 4 + 3] = fmaf(t, wv.w, acc[q * 4 + 3]);
            }
        }
    }
    const int oy = ty * 16 + tr, ox = tx * 16 + tc;
    size_t base = (((size_t)n * 64 + oy) * 64 + ox) * 32;
    #pragma unroll
    for (int q = 0; q < 4; ++q) {
        V16 o;
        #pragma unroll
        for (int j = 0; j < 8; ++j) o.s[j] = f2b(fmaxf(acc[q * 8 + j], 0.f));
        *(uint4*)&h1[base + q * 8] = o.u;
    }
}

// =================================================================
// MFMA conv k4s2: NHWC bf16 in/out.
// =================================================================
template <int CI, int CO, int HI, int WI, bool RELU>
__global__ __launch_bounds__(256)
void mfma_conv(const u16* __restrict__ xin, const u16* __restrict__ wt,
               const float* __restrict__ bias, u16* __restrict__ out) {
    constexpr int HO = HI / 2, WO = WI / 2;
    constexpr int BCOLS = (WO < 32) ? WO : 32;
    constexpr int XC = 2 * BCOLS + 2;
    constexpr int NCOLF = BCOLS / 16, NCOF = CO / 16, NCC = CI / 32;
    constexpr int CPU8 = CI / 8;
    __shared__ u16 sx[10 * XC * CI];

    int bid = blockIdx.x;
    constexpr int NBY = HO / 4, NTX = WO / BCOLS;
    const int tx = bid % NTX; bid /= NTX;
    const int by = bid % NBY; const int n = bid / NBY;
    const int oy0 = by * 4, ox0 = tx * BCOLS;
    const int tid = threadIdx.x, w = tid >> 6, lane = tid & 63;
    const int l15 = lane & 15, l4 = lane >> 4;

    const int iyb = 2 * oy0 - 1, ixb = 2 * ox0 - 1;
    for (int u = tid; u < 10 * XC * CPU8; u += 256) {
        int c8 = u % CPU8; int t2 = u / CPU8;
        int xc = t2 % XC; int r = t2 / XC;
        int iy = iyb + r, ix = ixb + xc;
        uint4 v = {0, 0, 0, 0};
        if (iy >= 0 && iy < HI && ix >= 0 && ix < WI)
            v = *(const uint4*)&xin[(((size_t)n * HI + iy) * WI + ix) * CI + c8 * 8];
        int byte = ((r * XC + xc) * CI + c8 * 8) * 2;
        byte ^= ((xc >> 1) & 7) << 4;
        *(uint4*)&sx[byte >> 1] = v;
    }
    __syncthreads();

    f32x4 acc[NCOLF][NCOF];
    #pragma unroll
    for (int pf = 0; pf < NCOLF; ++pf)
        #pragma unroll
        for (int cf = 0; cf < NCOF; ++cf) {
            float bv = bias[cf * 16 + l15];
            acc[pf][cf] = (f32x4){bv, bv, bv, bv};
        }

    #pragma unroll 2
    for (int tau = 0; tau < 16; ++tau) {
        const int ky = tau >> 2, kx = tau & 3;
        const int r = 2 * w + ky;
        #pragma unroll
        for (int cc = 0; cc < NCC; ++cc) {
            bf16x8 b[NCOF];
            #pragma unroll
            for (int cf = 0; cf < NCOF; ++cf)
                b[cf] = *(const bf16x8*)&wt[((size_t)(tau * CO + cf * 16 + l15)) * CI + cc * 32 + l4 * 8];
            bf16x8 a[NCOLF];
            #pragma unroll
            for (int pf = 0; pf < NCOLF; ++pf) {
                int xc = 2 * (pf * 16 + l15) + kx;
                int byte = ((r * XC + xc) * CI + cc * 32 + l4 * 8) * 2;
                byte ^= ((xc >> 1) & 7) << 4;
                a[pf] = *(const bf16x8*)&sx[byte >> 1];
            }
            #pragma unroll
            for (int pf = 0; pf < NCOLF; ++pf)
                #pragma unroll
                for (int cf = 0; cf < NCOF; ++cf)
                    acc[pf][cf] = __builtin_amdgcn_mfma_f32_16x16x32_bf16(
                        a[pf], b[cf], acc[pf][cf], 0, 0, 0);
        }
    }

    const int oy = oy0 + w;
    #pragma unroll
    for (int pf = 0; pf < NCOLF; ++pf)
        #pragma unroll
        for (int cf = 0; cf < NCOF; ++cf)
            #pragma unroll
            for (int rg = 0; rg < 4; ++rg) {
                int ox = ox0 + pf * 16 + l4 * 4 + rg;
                float v = acc[pf][cf][rg];
                if (RELU) v = fmaxf(v, 0.f);
                out[(((size_t)n * HO + oy) * WO + ox) * CO + cf * 16 + l15] = f2b(v);
            }
}

// =================================================================
// MFMA deconv k4s2, BOTH ry phases in one block (6 staged rows).
// relu -> bf16 NHWC.
// =================================================================
template <int CI, int CO, int HI, int WI>
__global__ __launch_bounds__(256)
void mfma_deconv2p(const u16* __restrict__ xin, const u16* __restrict__ wt,
                   const float* __restrict__ bias, u16* __restrict__ out) {
    constexpr int HO = 2 * HI, WO = 2 * WI;
    constexpr int BCOLS = (WI < 32) ? WI : 32;
    constexpr int XC = BCOLS + 2;
    constexpr int NCOLF = BCOLS / 16, NCOF = CO / 16, NCC = CI / 32;
    constexpr int CPU8 = CI / 8;
    __shared__ u16 sx[6 * XC * CI];

    int bid = blockIdx.x;
    constexpr int NBY = HI / 4, NTX = WI / BCOLS;
    const int tx = bid % NTX; bid /= NTX;
    const int by = bid % NBY; const int n = bid / NBY;
    const int q0 = by * 4, r0 = tx * BCOLS;
    const int tid = threadIdx.x, w = tid >> 6, lane = tid & 63;
    const int l15 = lane & 15, l4 = lane >> 4;

    // stage rows q0-1 .. q0+4
    const int qb0 = q0 - 1;
    for (int u = tid; u < 6 * XC * CPU8; u += 256) {
        int c8 = u % CPU8; int t2 = u / CPU8;
        int xc = t2 % XC; int r = t2 / XC;
        int iy = qb0 + r, ix = r0 - 1 + xc;
        uint4 v = {0, 0, 0, 0};
        if (iy >= 0 && iy < HI && ix >= 0 && ix < WI)
            v = *(const uint4*)&xin[(((size_t)n * HI + iy) * WI + ix) * CI + c8 * 8];
        int byte = ((r * XC + xc) * CI + c8 * 8) * 2;
        byte ^= (xc & 7) << 4;
        *(uint4*)&sx[byte >> 1] = v;
    }
    __syncthreads();

    f32x4 acc[2][2][NCOLF][NCOF];
    #pragma unroll
    for (int ry = 0; ry < 2; ++ry)
        #pragma unroll
        for (int rx = 0; rx < 2; ++rx)
            #pragma unroll
            for (int pf = 0; pf < NCOLF; ++pf)
                #pragma unroll
                for (int cf = 0; cf < NCOF; ++cf) {
                    float bv = bias[cf * 16 + l15];
                    acc[ry][rx][pf][cf] = (f32x4){bv, bv, bv, bv};
                }

    #pragma unroll
    for (int rx = 0; rx < 2; ++rx) {
        #pragma unroll 2
        for (int tap = 0; tap < 4; ++tap) {
            const int a_ = tap >> 1, b_ = tap & 1;
            #pragma unroll
            for (int cc = 0; cc < NCC; ++cc) {
                #pragma unroll
                for (int ry = 0; ry < 2; ++ry) {
                    const int r = ry + w + 1 - a_;
                    const int sidx = ry * 8 + rx * 4 + tap;
                    bf16x8 b[NCOF];
                    #pragma unroll
                    for (int cf = 0; cf < NCOF; ++cf)
                        b[cf] = *(const bf16x8*)&wt[((size_t)(sidx * CO + cf * 16 + l15)) * CI + cc * 32 + l4 * 8];
                    bf16x8 a[NCOLF];
                    #pragma unroll
                    for (int pf = 0; pf < NCOLF; ++pf) {
                        int xc = pf * 16 + l15 + rx - b_ + 1;
                        int byte = ((r * XC + xc) * CI + cc * 32 + l4 * 8) * 2;
                        byte ^= (xc & 7) << 4;
                        a[pf] = *(const bf16x8*)&sx[byte >> 1];
                    }
                    #pragma unroll
                    for (int pf = 0; pf < NCOLF; ++pf)
                        #pragma unroll
                        for (int cf = 0; cf < NCOF; ++cf)
                            acc[ry][rx][pf][cf] = __builtin_amdgcn_mfma_f32_16x16x32_bf16(
                                a[pf], b[cf], acc[ry][rx][pf][cf], 0, 0, 0);
                }
            }
        }
    }

    #pragma unroll
    for (int ry = 0; ry < 2; ++ry) {
        const int oy = 2 * (q0 + w) + ry;
        #pragma unroll
        for (int rx = 0; rx < 2; ++rx)
            #pragma unroll
            for (int pf = 0; pf < NCOLF; ++pf)
                #pragma unroll
                for (int cf = 0; cf < NCOF; ++cf)
                    #pragma unroll
                    for (int rg = 0; rg < 4; ++rg) {
                        int ox = 2 * (r0 + pf * 16 + l4 * 4 + rg) + rx;
                        float v = fmaxf(acc[ry][rx][pf][cf][rg], 0.f);
                        out[(((size_t)n * HO + oy) * WO + ox) * CO + cf * 16 + l15] = f2b(v);
                    }
    }
}

// =================================================================
// deconv3 direct VALU: g2 NHWC bf16 [128,64,64,32] -> x_recon f32 NCHW
// [128,3,128,128], fused sigmoid + recon-loss. Tile 16oy x 64ox.
// =================================================================
__global__ __launch_bounds__(256)
void deconv3_direct(const u16* __restrict__ g2, const float* __restrict__ d3,
                    const float* __restrict__ db3, float* __restrict__ out,
                    const float* __restrict__ ref, float* __restrict__ buckets) {
    __shared__ float sxf[32 * 10 * 35];   // [ci][r][col] f32, 44.8 KB
    __shared__ float sw[32 * 3 * 16];     // [ci][co][16], 6 KB
    int bid = blockIdx.x;
    const int tx = bid & 1; bid >>= 1;
    const int ty = bid & 7; const int n = bid >> 3;
    const int tid = threadIdx.x;
    const int cg = tid & 15, tr = tid >> 4;       // 16 col-groups x 16 rows
    const int tc0 = cg * 4;

    const int iy_org = ty * 8 - 1;
    const int ix_org = tx * 32 - 1;

    // stage g2 tile (10 rows x 34 cols x 32 ci), bf16 -> f32
    for (int u = tid; u < 10 * 34 * 4; u += 256) {
        int c8 = u & 3; int pos = u >> 2;
        int col = pos % 34; int r = pos / 34;
        int iy = iy_org + r, ix = ix_org + col;
        uint4 v = {0, 0, 0, 0};
        if (iy >= 0 && iy < 64 && ix >= 0 && ix < 64)
            v = *(const uint4*)&g2[(((size_t)n * 64 + iy) * 64 + ix) * 32 + c8 * 8];
        V16 vv; vv.u = v;
        #pragma unroll
        for (int j = 0; j < 8; ++j)
            sxf[((c8 * 8 + j) * 10 + r) * 35 + col] = b2f(vv.s[j]);
    }
    for (int l = tid; l < 1536; l += 256) sw[l] = d3[l];   // identity layout
    __syncthreads();

    const int ky0 = (tr + 1) & 1;
    const int iyA = ((tr + 1 - ky0) >> 1) + 1;
    const int iyB = iyA - 1;
    const int q = cg * 2;

    float acc[3][4];
    #pragma unroll
    for (int co = 0; co < 3; ++co) {
        float b = db3[co];
        #pragma unroll
        for (int p = 0; p < 4; ++p) acc[co][p] = b;
    }

    for (int ci = 0; ci < 32; ++ci) {
        float tA[4], tB[4];
        #pragma unroll
        for (int j = 0; j < 4; ++j) {
            tA[j] = sxf[(ci * 10 + iyA) * 35 + q + j];
            tB[j] = sxf[(ci * 10 + iyB) * 35 + q + j];
        }
        #pragma unroll
        for (int co = 0; co < 3; ++co) {
            const float4* wv = (const float4*)&sw[(ci * 3 + co) * 16];
            float4 wA = wv[ky0], wB = wv[ky0 + 2];
            #pragma unroll
            for (int p = 0; p < 4; ++p) {
                const int A = (p + 3) >> 1;
                const int B = (p + 1) >> 1;
                float a = acc[co][p];
                if (((p + 1) & 1) == 1) {     // kx0 = 1
                    a = fmaf(tA[A], wA.y, a);
                    a = fmaf(tA[B], wA.w, a);
                    a = fmaf(tB[A], wB.y, a);
                    a = fmaf(tB[B], wB.w, a);
                } else {                      // kx0 = 0
                    a = fmaf(tA[A], wA.x, a);
                    a = fmaf(tA[B], wA.z, a);
                    a = fmaf(tB[A], wB.x, a);
                    a = fmaf(tB[B], wB.z, a);
                }
                acc[co][p] = a;
            }
        }
    }

    const int oy = ty * 16 + tr, oxb = tx * 64 + tc0;
    float lsum = 0.f;
    #pragma unroll
    for (int co = 0; co < 3; ++co) {
        size_t oi = (((size_t)n * 3 + co) * 128 + oy) * 128 + oxb;
        float4 rf = *(const float4*)&ref[oi];
        float4 st;
        st.x = 1.f / (1.f + __expf(-acc[co][0]));
        st.y = 1.f / (1.f + __expf(-acc[co][1]));
        st.z = 1.f / (1.f + __expf(-acc[co][2]));
        st.w = 1.f / (1.f + __expf(-acc[co][3]));
        *(float4*)&out[oi] = st;
        float d0 = st.x - rf.x, d1 = st.y - rf.y, d2 = st.z - rf.z, d3v = st.w - rf.w;
        lsum += d0 * d0 + d1 * d1 + d2 * d2 + d3v * d3v;
    }
    #pragma unroll
    for (int off = 32; off; off >>= 1) lsum += __shfl_down(lsum, off, 64);
    if ((tid & 63) == 0) atomicAdd(&buckets[blockIdx.x & 255], lsum);
}

// =================================================================
// MFMA VQ: distances via z @ emb^T, wave-parallel argmin + fused gather.
// =================================================================
__global__ __launch_bounds__(256)
void vq_mfma(const u16* __restrict__ z, const float* __restrict__ emb,
             const float* __restrict__ e2g, u16* __restrict__ zq,
             float* __restrict__ vq_accum) {
    __shared__ u16 semb[NEMB * LAT];   // 32 KB, XOR-swizzled [code][k]
    __shared__ float se2[NEMB];        // 2 KB
    const int tid = threadIdx.x;

    for (int u = tid; u < 2048; u += 256) {
        int code = u >> 2, seg = u & 3;
        const float4* ep = (const float4*)&emb[code * 32 + seg * 8];
        float4 e0 = ep[0], e1 = ep[1];
        V16 o;
        o.s[0] = f2b(e0.x); o.s[1] = f2b(e0.y); o.s[2] = f2b(e0.z); o.s[3] = f2b(e0.w);
        o.s[4] = f2b(e1.x); o.s[5] = f2b(e1.y); o.s[6] = f2b(e1.z); o.s[7] = f2b(e1.w);
        int byte = (code * 64 + seg * 16) ^ ((code & 7) << 4);
        *(uint4*)((char*)semb + byte) = o.u;
    }
    if (tid < NEMB) se2[tid] = e2g[tid];
    __syncthreads();

    const int w = tid >> 6, lane = tid & 63;
    const int l15 = lane & 15, l4 = lane >> 4;
    const int rowbase = blockIdx.x * 64 + w * 16;

    bf16x8 a = *(const bf16x8*)&z[(size_t)(rowbase + l15) * LAT + l4 * 8];

    float best[4] = {1e30f, 1e30f, 1e30f, 1e30f};
    int   bidx[4] = {0, 0, 0, 0};
    #pragma unroll
    for (int f = 0; f < 32; ++f) {
        int byteb = ((f * 16 + l15) * 64 + l4 * 16) ^ ((l15 & 7) << 4);
        bf16x8 bfrag = *(const bf16x8*)((const char*)semb + byteb);
        f32x4 s = {0.f, 0.f, 0.f, 0.f};
        s = __builtin_amdgcn_mfma_f32_16x16x32_bf16(a, bfrag, s, 0, 0, 0);
        float e2c = se2[f * 16 + l15];
        int cidx = f * 16 + l15;
        #pragma unroll
        for (int j = 0; j < 4; ++j) {
            float d = fmaf(s[j], -2.f, e2c);
            bool lt = d < best[j];
            best[j] = lt ? d : best[j];
            bidx[j] = lt ? cidx : bidx[j];
        }
    }
    #pragma unroll
    for (int m = 1; m < 16; m <<= 1) {
        #pragma unroll
        for (int j = 0; j < 4; ++j) {
            float ob = __shfl_xor(best[j], m, 64);
            int   oi = __shfl_xor(bidx[j], m, 64);
            bool take = (ob < best[j]) || (ob == best[j] && oi < bidx[j]);
            best[j] = take ? ob : best[j];
            bidx[j] = take ? oi : bidx[j];
        }
    }
    const int r = lane >> 2;
    const int j0 = r & 3;
    int k = (j0 == 0) ? bidx[0] : (j0 == 1) ? bidx[1] : (j0 == 2) ? bidx[2] : bidx[3];
    const int seg = lane & 3;
    const float4* ep = (const float4*)&emb[k * LAT + seg * 8];
    float4 e0 = ep[0], e1 = ep[1];
    float ev[8] = {e0.x, e0.y, e0.z, e0.w, e1.x, e1.y, e1.z, e1.w};
    size_t zoff = (size_t)(rowbase + r) * LAT + seg * 8;
    V16 zr; zr.u = *(const uint4*)&z[zoff];
    V16 o;
    float local = 0.f;
    #pragma unroll
    for (int jj = 0; jj < 8; ++jj) {
        float dd = ev[jj] - b2f(zr.s[jj]);
        local = fmaf(dd, dd, local);
        o.s[jj] = f2b(ev[jj]);
    }
    *(uint4*)&zq[zoff] = o.u;
    #pragma unroll
    for (int off = 32; off; off >>= 1) local += __shfl_down(local, off, 64);
    if (lane == 0) atomicAdd(vq_accum, local);
}

__global__ void finalize_kernel(const float* __restrict__ accum, float* __restrict__ out,
                                int out_size) {
    int tid = threadIdx.x;  // 256
    float v = accum[tid];
    #pragma unroll
    for (int off = 32; off; off >>= 1) v += __shfl_down(v, off, 64);
    __shared__ float s[4];
    if ((tid & 63) == 0) s[tid >> 6] = v;
    __syncthreads();
    if (tid == 0) {
        float tot = s[0] + s[1] + s[2] + s[3];
        out[out_size - 2] = tot / 6291456.f;                 // recon_loss
        out[out_size - 1] = 1.25f * accum[256] / 1048576.f;  // vq_loss
    }
}

extern "C" void kernel_launch(void* const* d_in, const int* in_sizes, int n_in,
                              void* d_out, int out_size, void* d_ws, size_t ws_size,
                              hipStream_t stream) {
    const float* x   = (const float*)d_in[0];
    const float* w1  = (const float*)d_in[1];
    const float* b1  = (const float*)d_in[2];
    const float* w2  = (const float*)d_in[3];
    const float* b2  = (const float*)d_in[4];
    const float* w3  = (const float*)d_in[5];
    const float* b3  = (const float*)d_in[6];
    const float* emb = (const float*)d_in[7];
    const float* d1  = (const float*)d_in[8];
    const float* db1 = (const float*)d_in[9];
    const float* d2  = (const float*)d_in[10];
    const float* db2 = (const float*)d_in[11];
    const float* d3  = (const float*)d_in[12];
    const float* db3 = (const float*)d_in[13];

    char* ws = (char*)d_ws;
    u16* h1  = (u16*)(ws + OFF_H1);    // also g2
    u16* h2  = (u16*)(ws + OFF_H2);    // also g1
    u16* zb  = (u16*)(ws + OFF_Z);
    u16* zqb = (u16*)(ws + OFF_ZQ);
    u16* w2t = (u16*)(ws + OFF_W2T);
    u16* w3t = (u16*)(ws + OFF_W3T);
    u16* d1t = (u16*)(ws + OFF_D1T);
    u16* d2t = (u16*)(ws + OFF_D2T);
    float* acc = (float*)(ws + OFF_ACC);
    float* e2  = (float*)(ws + OFF_E2);
    float* out = (float*)d_out;

    prep_kernel<<<516, 256, 0, stream>>>(w2, w3, d1, d2, emb,
                                         w2t, w3t, d1t, d2t, acc, e2);

    // encoder
    conv1_direct<<<2048, 256, 0, stream>>>(x, w1, b1, h1);
    mfma_conv<32, 64, 64, 64, true ><<<1024, 256, 0, stream>>>(h1, w2t, b2, h2);
    mfma_conv<64, 32, 32, 32, false><<<512, 256, 0, stream>>>(h2, w3t, b3, zb);

    // vector quantization
    vq_mfma<<<512, 256, 0, stream>>>(zb, emb, e2, zqb, acc + 256);

    // decoder (g1 reuses h2 space, g2 reuses h1 space)
    u16* g1 = h2; u16* g2 = h1;
    mfma_deconv2p<32, 64, 16, 16><<<512, 256, 0, stream>>>(zqb, d1t, db1, g1);
    mfma_deconv2p<64, 32, 32, 32><<<1024, 256, 0, stream>>>(g1, d2t, db2, g2);
    deconv3_direct<<<2048, 256, 0, stream>>>(g2, d3, db3, out, x, acc);

    finalize_kernel<<<1, 256, 0, stream>>>(acc, out, out_size);
}

// Round 6
// 234.310 us; speedup vs baseline: 26.9476x; 1.0136x over previous
//
#include <hip/hip_runtime.h>
#include <math.h>

#define NEMB 512
#define LAT 32

typedef unsigned short u16;
typedef unsigned int u32;
typedef __attribute__((ext_vector_type(8))) short bf16x8;   // 8 bf16 in 4 VGPRs
typedef __attribute__((ext_vector_type(4))) float f32x4;

__device__ __forceinline__ u16 f2b(float f) {               // fp32 -> bf16 RTNE
    unsigned u = __builtin_bit_cast(unsigned, f);
    return (u16)((u + 0x7fffu + ((u >> 16) & 1u)) >> 16);
}
__device__ __forceinline__ float b2f(u16 h) {
    unsigned u = ((unsigned)h) << 16;
    return __builtin_bit_cast(float, u);
}
__device__ __forceinline__ float b2f_lo(u32 u) { return __builtin_bit_cast(float, u << 16); }
__device__ __forceinline__ float b2f_hi(u32 u) { return __builtin_bit_cast(float, u & 0xffff0000u); }

union V16 { uint4 u; u16 s[8]; };

// ---------------- workspace layout (BYTES) ----------------
static const size_t OFF_H1  = 0;          // h1 [128,64,64,32] bf16 (later g2)
static const size_t OFF_H2  = 33554432;   // h2 [128,32,32,64] bf16 (later g1)
static const size_t OFF_Z   = 50331648;   // z  [128,16,16,32] bf16
static const size_t OFF_ZQ  = 52428800;   // zq [128,16,16,32] bf16
static const size_t OFF_W2T = 54525952;   // [16][64][32] bf16
static const size_t OFF_W3T = 54591488;   // [16][32][64] bf16
static const size_t OFF_D1T = 54657024;   // [16][64][32] bf16
static const size_t OFF_D2T = 54722560;   // [16][32][64] bf16
static const size_t OFF_ACC = 54804480;   // f32: [0..255] recon buckets, [256] vq sum
static const size_t OFF_E2  = 54806528;   // f32: per-code ||e||^2

// =================================================================
// prep: weight transforms + e2 + accumulator zeroing in ONE kernel
// =================================================================
__global__ __launch_bounds__(256)
void prep_kernel(const float* __restrict__ w2, const float* __restrict__ w3,
                 const float* __restrict__ d1, const float* __restrict__ d2,
                 const float* __restrict__ emb,
                 u16* __restrict__ w2t, u16* __restrict__ w3t, u16* __restrict__ d1t,
                 u16* __restrict__ d2t,
                 float* __restrict__ accum, float* __restrict__ e2) {
    int t = blockIdx.x * 256 + threadIdx.x;
    if (t < 32768) {                       // w2: conv, CO=64 CI=32 -> [tau][co][ci]
        int ci = t & 31; int t2 = t >> 5; int co = t2 & 63; int tau = t2 >> 6;
        w2t[t] = f2b(w2[((size_t)co * 32 + ci) * 16 + tau]);
    } else if (t < 65536) {                // w3: conv, CO=32 CI=64
        int u = t - 32768;
        int ci = u & 63; int t2 = u >> 6; int co = t2 & 31; int tau = t2 >> 5;
        w3t[u] = f2b(w3[((size_t)co * 64 + ci) * 16 + tau]);
    } else if (t < 98304) {                // d1: deconv, CO=64 CI=32 -> [s][co][ci]
        int u = t - 65536;
        int ci = u & 31; int t2 = u >> 5; int co = t2 & 63; int s = t2 >> 6;
        int ry = (s >> 3) & 1, rx = (s >> 2) & 1, a = (s >> 1) & 1, b = s & 1;
        int ky = ((ry + 1) & 1) + 2 * a, kx = ((rx + 1) & 1) + 2 * b;
        d1t[u] = f2b(d1[((size_t)ci * 64 + co) * 16 + ky * 4 + kx]);
    } else if (t < 131072) {               // d2: deconv, CO=32 CI=64
        int u = t - 98304;
        int ci = u & 63; int t2 = u >> 6; int co = t2 & 31; int s = t2 >> 5;
        int ry = (s >> 3) & 1, rx = (s >> 2) & 1, a = (s >> 1) & 1, b = s & 1;
        int ky = ((ry + 1) & 1) + 2 * a, kx = ((rx + 1) & 1) + 2 * b;
        d2t[u] = f2b(d2[((size_t)ci * 32 + co) * 16 + ky * 4 + kx]);
    } else if (t < 131584) {               // e2
        int u = t - 131072;
        float s = 0.f;
        #pragma unroll
        for (int c = 0; c < LAT; ++c) { float e = emb[u * LAT + c]; s = fmaf(e, e, s); }
        e2[u] = s;
    } else if (t < 131904) {               // zero accumulators
        accum[t - 131584] = 0.f;
    }
}

// =================================================================
// conv1 direct: x NCHW f32 [128,3,128,128] -> h1 NHWC bf16 [128,64,64,32]
// =================================================================
__global__ __launch_bounds__(256)
void conv1_direct(const float* __restrict__ x, const float* __restrict__ w1,
                  const float* __restrict__ b1, u16* __restrict__ h1) {
    __shared__ float sx[3 * 34 * 35];
    __shared__ float sw[3 * 16 * 32];   // [ci][kykx][co]
    int bid = blockIdx.x;
    const int tx = bid % 4; bid /= 4;
    const int ty = bid % 4; const int n = bid / 4;
    const int tid = threadIdx.x, tr = tid >> 4, tc = tid & 15;

    for (int u = tid; u < 3 * 34 * 34; u += 256) {
        int c = u / 1156; int rem = u % 1156; int r = rem / 34; int col = rem % 34;
        int iy = ty * 32 - 1 + r, ix = tx * 32 - 1 + col;
        float v = 0.f;
        if (iy >= 0 && iy < 128 && ix >= 0 && ix < 128)
            v = x[(((size_t)n * 3 + c) * 128 + iy) * 128 + ix];
        sx[(c * 34 + r) * 35 + col] = v;
    }
    for (int l = tid; l < 1536; l += 256) {
        int co = l & 31, kykx = (l >> 5) & 15, ci = l >> 9;
        sw[l] = w1[((size_t)co * 3 + ci) * 16 + kykx];
    }
    __syncthreads();

    float acc[32];
    #pragma unroll
    for (int c = 0; c < 32; ++c) acc[c] = b1[c];

    for (int ci = 0; ci < 3; ++ci) {
        float tv[16];
        #pragma unroll
        for (int ky = 0; ky < 4; ++ky)
            #pragma unroll
            for (int kx = 0; kx < 4; ++kx)
                tv[ky * 4 + kx] = sx[(ci * 34 + 2 * tr + ky) * 35 + 2 * tc + kx];
        #pragma unroll
        for (int kk = 0; kk < 16; ++kk) {
            float t = tv[kk];
            const float4* wp = (const float4*)&sw[(ci * 16 + kk) * 32];
            #pragma unroll
            for (int q = 0; q < 8; ++q) {
                float4 wv = wp[q];
                acc[q * 4 + 0] = fmaf(t, wv.x, acc[q * 4 + 0]);
                acc[q * 4 + 1] = fmaf(t, wv.y, acc[q * 4 + 1]);
                acc[q * 4 + 2] = fmaf(t, wv.z, acc[q * 4 + 2]);
                acc[q * 4 + 3] = fmaf(t, wv.w, acc[q * 4 + 3]);
            }
        }
    }
    const int oy = ty * 16 + tr, ox = tx * 16 + tc;
    size_t base = (((size_t)n * 64 + oy) * 64 + ox) * 32;
    #pragma unroll
    for (int q = 0; q < 4; ++q) {
        V16 o;
        #pragma unroll
        for (int j = 0; j < 8; ++j) o.s[j] = f2b(fmaxf(acc[q * 8 + j], 0.f));
        *(uint4*)&h1[base + q * 8] = o.u;
    }
}

// =================================================================
// MFMA conv k4s2: NHWC bf16 in/out.
// =================================================================
template <int CI, int CO, int HI, int WI, bool RELU>
__global__ __launch_bounds__(256)
void mfma_conv(const u16* __restrict__ xin, const u16* __restrict__ wt,
               const float* __restrict__ bias, u16* __restrict__ out) {
    constexpr int HO = HI / 2, WO = WI / 2;
    constexpr int BCOLS = (WO < 32) ? WO : 32;
    constexpr int XC = 2 * BCOLS + 2;
    constexpr int NCOLF = BCOLS / 16, NCOF = CO / 16, NCC = CI / 32;
    constexpr int CPU8 = CI / 8;
    __shared__ u16 sx[10 * XC * CI];

    int bid = blockIdx.x;
    constexpr int NBY = HO / 4, NTX = WO / BCOLS;
    const int tx = bid % NTX; bid /= NTX;
    const int by = bid % NBY; const int n = bid / NBY;
    const int oy0 = by * 4, ox0 = tx * BCOLS;
    const int tid = threadIdx.x, w = tid >> 6, lane = tid & 63;
    const int l15 = lane & 15, l4 = lane >> 4;

    const int iyb = 2 * oy0 - 1, ixb = 2 * ox0 - 1;
    for (int u = tid; u < 10 * XC * CPU8; u += 256) {
        int c8 = u % CPU8; int t2 = u / CPU8;
        int xc = t2 % XC; int r = t2 / XC;
        int iy = iyb + r, ix = ixb + xc;
        uint4 v = {0, 0, 0, 0};
        if (iy >= 0 && iy < HI && ix >= 0 && ix < WI)
            v = *(const uint4*)&xin[(((size_t)n * HI + iy) * WI + ix) * CI + c8 * 8];
        int byte = ((r * XC + xc) * CI + c8 * 8) * 2;
        byte ^= ((xc >> 1) & 7) << 4;
        *(uint4*)&sx[byte >> 1] = v;
    }
    __syncthreads();

    f32x4 acc[NCOLF][NCOF];
    #pragma unroll
    for (int pf = 0; pf < NCOLF; ++pf)
        #pragma unroll
        for (int cf = 0; cf < NCOF; ++cf) {
            float bv = bias[cf * 16 + l15];
            acc[pf][cf] = (f32x4){bv, bv, bv, bv};
        }

    #pragma unroll 2
    for (int tau = 0; tau < 16; ++tau) {
        const int ky = tau >> 2, kx = tau & 3;
        const int r = 2 * w + ky;
        #pragma unroll
        for (int cc = 0; cc < NCC; ++cc) {
            bf16x8 b[NCOF];
            #pragma unroll
            for (int cf = 0; cf < NCOF; ++cf)
                b[cf] = *(const bf16x8*)&wt[((size_t)(tau * CO + cf * 16 + l15)) * CI + cc * 32 + l4 * 8];
            bf16x8 a[NCOLF];
            #pragma unroll
            for (int pf = 0; pf < NCOLF; ++pf) {
                int xc = 2 * (pf * 16 + l15) + kx;
                int byte = ((r * XC + xc) * CI + cc * 32 + l4 * 8) * 2;
                byte ^= ((xc >> 1) & 7) << 4;
                a[pf] = *(const bf16x8*)&sx[byte >> 1];
            }
            #pragma unroll
            for (int pf = 0; pf < NCOLF; ++pf)
                #pragma unroll
                for (int cf = 0; cf < NCOF; ++cf)
                    acc[pf][cf] = __builtin_amdgcn_mfma_f32_16x16x32_bf16(
                        a[pf], b[cf], acc[pf][cf], 0, 0, 0);
        }
    }

    const int oy = oy0 + w;
    #pragma unroll
    for (int pf = 0; pf < NCOLF; ++pf)
        #pragma unroll
        for (int cf = 0; cf < NCOF; ++cf)
            #pragma unroll
            for (int rg = 0; rg < 4; ++rg) {
                int ox = ox0 + pf * 16 + l4 * 4 + rg;
                float v = acc[pf][cf][rg];
                if (RELU) v = fmaxf(v, 0.f);
                out[(((size_t)n * HO + oy) * WO + ox) * CO + cf * 16 + l15] = f2b(v);
            }
}

// =================================================================
// MFMA deconv k4s2, BOTH ry phases in one block (6 staged rows).
// relu -> bf16 NHWC.
// =================================================================
template <int CI, int CO, int HI, int WI>
__global__ __launch_bounds__(256)
void mfma_deconv2p(const u16* __restrict__ xin, const u16* __restrict__ wt,
                   const float* __restrict__ bias, u16* __restrict__ out) {
    constexpr int HO = 2 * HI, WO = 2 * WI;
    constexpr int BCOLS = (WI < 32) ? WI : 32;
    constexpr int XC = BCOLS + 2;
    constexpr int NCOLF = BCOLS / 16, NCOF = CO / 16, NCC = CI / 32;
    constexpr int CPU8 = CI / 8;
    __shared__ u16 sx[6 * XC * CI];

    int bid = blockIdx.x;
    constexpr int NBY = HI / 4, NTX = WI / BCOLS;
    const int tx = bid % NTX; bid /= NTX;
    const int by = bid % NBY; const int n = bid / NBY;
    const int q0 = by * 4, r0 = tx * BCOLS;
    const int tid = threadIdx.x, w = tid >> 6, lane = tid & 63;
    const int l15 = lane & 15, l4 = lane >> 4;

    // stage rows q0-1 .. q0+4
    const int qb0 = q0 - 1;
    for (int u = tid; u < 6 * XC * CPU8; u += 256) {
        int c8 = u % CPU8; int t2 = u / CPU8;
        int xc = t2 % XC; int r = t2 / XC;
        int iy = qb0 + r, ix = r0 - 1 + xc;
        uint4 v = {0, 0, 0, 0};
        if (iy >= 0 && iy < HI && ix >= 0 && ix < WI)
            v = *(const uint4*)&xin[(((size_t)n * HI + iy) * WI + ix) * CI + c8 * 8];
        int byte = ((r * XC + xc) * CI + c8 * 8) * 2;
        byte ^= (xc & 7) << 4;
        *(uint4*)&sx[byte >> 1] = v;
    }
    __syncthreads();

    f32x4 acc[2][2][NCOLF][NCOF];
    #pragma unroll
    for (int ry = 0; ry < 2; ++ry)
        #pragma unroll
        for (int rx = 0; rx < 2; ++rx)
            #pragma unroll
            for (int pf = 0; pf < NCOLF; ++pf)
                #pragma unroll
                for (int cf = 0; cf < NCOF; ++cf) {
                    float bv = bias[cf * 16 + l15];
                    acc[ry][rx][pf][cf] = (f32x4){bv, bv, bv, bv};
                }

    #pragma unroll
    for (int rx = 0; rx < 2; ++rx) {
        #pragma unroll 2
        for (int tap = 0; tap < 4; ++tap) {
            const int a_ = tap >> 1, b_ = tap & 1;
            #pragma unroll
            for (int cc = 0; cc < NCC; ++cc) {
                #pragma unroll
                for (int ry = 0; ry < 2; ++ry) {
                    const int r = ry + w + 1 - a_;
                    const int sidx = ry * 8 + rx * 4 + tap;
                    bf16x8 b[NCOF];
                    #pragma unroll
                    for (int cf = 0; cf < NCOF; ++cf)
                        b[cf] = *(const bf16x8*)&wt[((size_t)(sidx * CO + cf * 16 + l15)) * CI + cc * 32 + l4 * 8];
                    bf16x8 a[NCOLF];
                    #pragma unroll
                    for (int pf = 0; pf < NCOLF; ++pf) {
                        int xc = pf * 16 + l15 + rx - b_ + 1;
                        int byte = ((r * XC + xc) * CI + cc * 32 + l4 * 8) * 2;
                        byte ^= (xc & 7) << 4;
                        a[pf] = *(const bf16x8*)&sx[byte >> 1];
                    }
                    #pragma unroll
                    for (int pf = 0; pf < NCOLF; ++pf)
                        #pragma unroll
                        for (int cf = 0; cf < NCOF; ++cf)
                            acc[ry][rx][pf][cf] = __builtin_amdgcn_mfma_f32_16x16x32_bf16(
                                a[pf], b[cf], acc[ry][rx][pf][cf], 0, 0, 0);
                }
            }
        }
    }

    #pragma unroll
    for (int ry = 0; ry < 2; ++ry) {
        const int oy = 2 * (q0 + w) + ry;
        #pragma unroll
        for (int rx = 0; rx < 2; ++rx)
            #pragma unroll
            for (int pf = 0; pf < NCOLF; ++pf)
                #pragma unroll
                for (int cf = 0; cf < NCOF; ++cf)
                    #pragma unroll
                    for (int rg = 0; rg < 4; ++rg) {
                        int ox = 2 * (r0 + pf * 16 + l4 * 4 + rg) + rx;
                        float v = fmaxf(acc[ry][rx][pf][cf][rg], 0.f);
                        out[(((size_t)n * HO + oy) * WO + ox) * CO + cf * 16 + l15] = f2b(v);
                    }
    }
}

// =================================================================
// deconv3 direct VALU v2: g2 NHWC bf16 [128,64,64,32] -> x_recon f32 NCHW
// [128,3,128,128], fused sigmoid + recon-loss.
// Tile 16 oy x 128 ox (full width). LDS taps as ci-pair planes:
// sxp[c2][10 r][68 col] of u32 (2 bf16), plane stride 684 (2-way bank max).
// Per ci-pair: 2 ds_read_b128 + 2 ds_read_b64 taps (was 16 ds_read_b32).
// =================================================================
__global__ __launch_bounds__(256)
void deconv3_direct(const u16* __restrict__ g2, const float* __restrict__ d3,
                    const float* __restrict__ db3, float* __restrict__ out,
                    const float* __restrict__ ref, float* __restrict__ buckets) {
    __shared__ u32 sxp[16 * 684];         // 43.8 KB
    __shared__ float sw[32 * 3 * 16];     // [ci][co][16], 6 KB
    int bid = blockIdx.x;
    const int ty = bid & 7; const int n = bid >> 3;
    const int tid = threadIdx.x;
    const int tr = tid >> 4, cg = tid & 15;     // 16 rows x 16 col-groups (PPT=8)

    const int iy_org = ty * 8 - 1;

    // stage g2 tile (10 rows x 66 cols x 32 ci) into ci-pair planes
    for (int u = tid; u < 10 * 66 * 4; u += 256) {
        int c8 = u & 3; int pos = u >> 2;
        int col = pos % 66; int r = pos / 66;
        int iy = iy_org + r, ix = col - 1;
        uint4 v = {0, 0, 0, 0};
        if (iy >= 0 && iy < 64 && ix >= 0 && ix < 64)
            v = *(const uint4*)&g2[(((size_t)n * 64 + iy) * 64 + ix) * 32 + c8 * 8];
        int base = r * 68 + col;
        sxp[(c8 * 4 + 0) * 684 + base] = v.x;
        sxp[(c8 * 4 + 1) * 684 + base] = v.y;
        sxp[(c8 * 4 + 2) * 684 + base] = v.z;
        sxp[(c8 * 4 + 3) * 684 + base] = v.w;
    }
    for (int l = tid; l < 1536; l += 256) sw[l] = d3[l];   // identity layout
    __syncthreads();

    const int ky0 = (tr + 1) & 1;
    const int iyA = ((tr + 1 - ky0) >> 1) + 1;   // local tap rows
    const int iyB = iyA - 1;
    const int q = cg * 4;                        // local tap col base

    float acc[3][8];
    #pragma unroll
    for (int co = 0; co < 3; ++co) {
        float b = db3[co];
        #pragma unroll
        for (int p = 0; p < 8; ++p) acc[co][p] = b;
    }

    #pragma unroll 1
    for (int c2 = 0; c2 < 16; ++c2) {
        // taps for the ci-pair: cols q..q+5, rows iyA/iyB
        u32 ta[6], tb[6];
        {
            uint4 hA  = *(const uint4*)&sxp[c2 * 684 + iyA * 68 + q];
            uint2 hA2 = *(const uint2*)&sxp[c2 * 684 + iyA * 68 + q + 4];
            uint4 hB  = *(const uint4*)&sxp[c2 * 684 + iyB * 68 + q];
            uint2 hB2 = *(const uint2*)&sxp[c2 * 684 + iyB * 68 + q + 4];
            ta[0] = hA.x; ta[1] = hA.y; ta[2] = hA.z; ta[3] = hA.w; ta[4] = hA2.x; ta[5] = hA2.y;
            tb[0] = hB.x; tb[1] = hB.y; tb[2] = hB.z; tb[3] = hB.w; tb[4] = hB2.x; tb[5] = hB2.y;
        }
        #pragma unroll
        for (int cc = 0; cc < 2; ++cc) {
            const int ci = 2 * c2 + cc;
            float tA[6], tB[6];
            #pragma unroll
            for (int j = 0; j < 6; ++j) {
                tA[j] = cc ? b2f_hi(ta[j]) : b2f_lo(ta[j]);
                tB[j] = cc ? b2f_hi(tb[j]) : b2f_lo(tb[j]);
            }
            #pragma unroll
            for (int co = 0; co < 3; ++co) {
                const float4* wv = (const float4*)&sw[(ci * 3 + co) * 16];
                float4 wA = wv[ky0], wB = wv[ky0 + 2];
                #pragma unroll
                for (int p = 0; p < 8; ++p) {
                    const int A = (p + 3) >> 1;
                    const int B = (p + 1) >> 1;
                    float a = acc[co][p];
                    if (((p + 1) & 1) == 1) {     // p even -> kx0 = 1
                        a = fmaf(tA[A], wA.y, a);
                        a = fmaf(tA[B], wA.w, a);
                        a = fmaf(tB[A], wB.y, a);
                        a = fmaf(tB[B], wB.w, a);
                    } else {                      // p odd -> kx0 = 0
                        a = fmaf(tA[A], wA.x, a);
                        a = fmaf(tA[B], wA.z, a);
                        a = fmaf(tB[A], wB.x, a);
                        a = fmaf(tB[B], wB.z, a);
                    }
                    acc[co][p] = a;
                }
            }
        }
    }

    const int oy = ty * 16 + tr, oxb = cg * 8;
    float lsum = 0.f;
    #pragma unroll
    for (int co = 0; co < 3; ++co) {
        size_t oi = (((size_t)n * 3 + co) * 128 + oy) * 128 + oxb;
        #pragma unroll
        for (int h = 0; h < 2; ++h) {
            float4 rf = *(const float4*)&ref[oi + h * 4];
            float4 st;
            st.x = 1.f / (1.f + __expf(-acc[co][h * 4 + 0]));
            st.y = 1.f / (1.f + __expf(-acc[co][h * 4 + 1]));
            st.z = 1.f / (1.f + __expf(-acc[co][h * 4 + 2]));
            st.w = 1.f / (1.f + __expf(-acc[co][h * 4 + 3]));
            *(float4*)&out[oi + h * 4] = st;
            float d0 = st.x - rf.x, d1 = st.y - rf.y, d2 = st.z - rf.z, d3v = st.w - rf.w;
            lsum += d0 * d0 + d1 * d1 + d2 * d2 + d3v * d3v;
        }
    }
    #pragma unroll
    for (int off = 32; off; off >>= 1) lsum += __shfl_down(lsum, off, 64);
    if ((tid & 63) == 0) atomicAdd(&buckets[blockIdx.x & 255], lsum);
}

// =================================================================
// MFMA VQ: distances via z @ emb^T, wave-parallel argmin + fused gather.
// =================================================================
__global__ __launch_bounds__(256)
void vq_mfma(const u16* __restrict__ z, const float* __restrict__ emb,
             const float* __restrict__ e2g, u16* __restrict__ zq,
             float* __restrict__ vq_accum) {
    __shared__ u16 semb[NEMB * LAT];   // 32 KB, XOR-swizzled [code][k]
    __shared__ float se2[NEMB];        // 2 KB
    const int tid = threadIdx.x;

    for (int u = tid; u < 2048; u += 256) {
        int code = u >> 2, seg = u & 3;
        const float4* ep = (const float4*)&emb[code * 32 + seg * 8];
        float4 e0 = ep[0], e1 = ep[1];
        V16 o;
        o.s[0] = f2b(e0.x); o.s[1] = f2b(e0.y); o.s[2] = f2b(e0.z); o.s[3] = f2b(e0.w);
        o.s[4] = f2b(e1.x); o.s[5] = f2b(e1.y); o.s[6] = f2b(e1.z); o.s[7] = f2b(e1.w);
        int byte = (code * 64 + seg * 16) ^ ((code & 7) << 4);
        *(uint4*)((char*)semb + byte) = o.u;
    }
    if (tid < NEMB) se2[tid] = e2g[tid];
    __syncthreads();

    const int w = tid >> 6, lane = tid & 63;
    const int l15 = lane & 15, l4 = lane >> 4;
    const int rowbase = blockIdx.x * 64 + w * 16;

    bf16x8 a = *(const bf16x8*)&z[(size_t)(rowbase + l15) * LAT + l4 * 8];

    float best[4] = {1e30f, 1e30f, 1e30f, 1e30f};
    int   bidx[4] = {0, 0, 0, 0};
    #pragma unroll
    for (int f = 0; f < 32; ++f) {
        int byteb = ((f * 16 + l15) * 64 + l4 * 16) ^ ((l15 & 7) << 4);
        bf16x8 bfrag = *(const bf16x8*)((const char*)semb + byteb);
        f32x4 s = {0.f, 0.f, 0.f, 0.f};
        s = __builtin_amdgcn_mfma_f32_16x16x32_bf16(a, bfrag, s, 0, 0, 0);
        float e2c = se2[f * 16 + l15];
        int cidx = f * 16 + l15;
        #pragma unroll
        for (int j = 0; j < 4; ++j) {
            float d = fmaf(s[j], -2.f, e2c);
            bool lt = d < best[j];
            best[j] = lt ? d : best[j];
            bidx[j] = lt ? cidx : bidx[j];
        }
    }
    #pragma unroll
    for (int m = 1; m < 16; m <<= 1) {
        #pragma unroll
        for (int j = 0; j < 4; ++j) {
            float ob = __shfl_xor(best[j], m, 64);
            int   oi = __shfl_xor(bidx[j], m, 64);
            bool take = (ob < best[j]) || (ob == best[j] && oi < bidx[j]);
            best[j] = take ? ob : best[j];
            bidx[j] = take ? oi : bidx[j];
        }
    }
    const int r = lane >> 2;
    const int j0 = r & 3;
    int k = (j0 == 0) ? bidx[0] : (j0 == 1) ? bidx[1] : (j0 == 2) ? bidx[2] : bidx[3];
    const int seg = lane & 3;
    const float4* ep = (const float4*)&emb[k * LAT + seg * 8];
    float4 e0 = ep[0], e1 = ep[1];
    float ev[8] = {e0.x, e0.y, e0.z, e0.w, e1.x, e1.y, e1.z, e1.w};
    size_t zoff = (size_t)(rowbase + r) * LAT + seg * 8;
    V16 zr; zr.u = *(const uint4*)&z[zoff];
    V16 o;
    float local = 0.f;
    #pragma unroll
    for (int jj = 0; jj < 8; ++jj) {
        float dd = ev[jj] - b2f(zr.s[jj]);
        local = fmaf(dd, dd, local);
        o.s[jj] = f2b(ev[jj]);
    }
    *(uint4*)&zq[zoff] = o.u;
    #pragma unroll
    for (int off = 32; off; off >>= 1) local += __shfl_down(local, off, 64);
    if (lane == 0) atomicAdd(vq_accum, local);
}

__global__ void finalize_kernel(const float* __restrict__ accum, float* __restrict__ out,
                                int out_size) {
    int tid = threadIdx.x;  // 256
    float v = accum[tid];
    #pragma unroll
    for (int off = 32; off; off >>= 1) v += __shfl_down(v, off, 64);
    __shared__ float s[4];
    if ((tid & 63) == 0) s[tid >> 6] = v;
    __syncthreads();
    if (tid == 0) {
        float tot = s[0] + s[1] + s[2] + s[3];
        out[out_size - 2] = tot / 6291456.f;                 // recon_loss
        out[out_size - 1] = 1.25f * accum[256] / 1048576.f;  // vq_loss
    }
}

extern "C" void kernel_launch(void* const* d_in, const int* in_sizes, int n_in,
                              void* d_out, int out_size, void* d_ws, size_t ws_size,
                              hipStream_t stream) {
    const float* x   = (const float*)d_in[0];
    const float* w1  = (const float*)d_in[1];
    const float* b1  = (const float*)d_in[2];
    const float* w2  = (const float*)d_in[3];
    const float* b2  = (const float*)d_in[4];
    const float* w3  = (const float*)d_in[5];
    const float* b3  = (const float*)d_in[6];
    const float* emb = (const float*)d_in[7];
    const float* d1  = (const float*)d_in[8];
    const float* db1 = (const float*)d_in[9];
    const float* d2  = (const float*)d_in[10];
    const float* db2 = (const float*)d_in[11];
    const float* d3  = (const float*)d_in[12];
    const float* db3 = (const float*)d_in[13];

    char* ws = (char*)d_ws;
    u16* h1  = (u16*)(ws + OFF_H1);    // also g2
    u16* h2  = (u16*)(ws + OFF_H2);    // also g1
    u16* zb  = (u16*)(ws + OFF_Z);
    u16* zqb = (u16*)(ws + OFF_ZQ);
    u16* w2t = (u16*)(ws + OFF_W2T);
    u16* w3t = (u16*)(ws + OFF_W3T);
    u16* d1t = (u16*)(ws + OFF_D1T);
    u16* d2t = (u16*)(ws + OFF_D2T);
    float* acc = (float*)(ws + OFF_ACC);
    float* e2  = (float*)(ws + OFF_E2);
    float* out = (float*)d_out;

    prep_kernel<<<516, 256, 0, stream>>>(w2, w3, d1, d2, emb,
                                         w2t, w3t, d1t, d2t, acc, e2);

    // encoder
    conv1_direct<<<2048, 256, 0, stream>>>(x, w1, b1, h1);
    mfma_conv<32, 64, 64, 64, true ><<<1024, 256, 0, stream>>>(h1, w2t, b2, h2);
    mfma_conv<64, 32, 32, 32, false><<<512, 256, 0, stream>>>(h2, w3t, b3, zb);

    // vector quantization
    vq_mfma<<<512, 256, 0, stream>>>(zb, emb, e2, zqb, acc + 256);

    // decoder (g1 reuses h2 space, g2 reuses h1 space)
    u16* g1 = h2; u16* g2 = h1;
    mfma_deconv2p<32, 64, 16, 16><<<512, 256, 0, stream>>>(zqb, d1t, db1, g1);
    mfma_deconv2p<64, 32, 32, 32><<<1024, 256, 0, stream>>>(g1, d2t, db2, g2);
    deconv3_direct<<<1024, 256, 0, stream>>>(g2, d3, db3, out, x, acc);

    finalize_kernel<<<1, 256, 0, stream>>>(acc, out, out_size);
}